// Round 1
// baseline (750.602 us; speedup 1.0000x reference)
//
#include <hip/hip_runtime.h>

// ---------------- CSR build ----------------

__global__ void k_count(const int* __restrict__ dst, int* __restrict__ cnt, int E) {
    int e = blockIdx.x * blockDim.x + threadIdx.x;
    if (e < E) atomicAdd(&cnt[dst[e]], 1);
}

__global__ void k_dinv(const int* __restrict__ cnt, float* __restrict__ dinv, int N) {
    int i = blockIdx.x * blockDim.x + threadIdx.x;
    if (i < N) dinv[i] = rsqrtf((float)(cnt[i] + 1));  // +1 self-loop
}

__global__ void k_scan1(const int* __restrict__ cnt, int* __restrict__ offs,
                        int* __restrict__ bsums, int N) {
    __shared__ int tmp[1024];
    int tid = threadIdx.x;
    int i = blockIdx.x * 1024 + tid;
    int v = (i < N) ? cnt[i] : 0;
    tmp[tid] = v;
    __syncthreads();
    for (int d = 1; d < 1024; d <<= 1) {
        int t = (tid >= d) ? tmp[tid - d] : 0;
        __syncthreads();
        tmp[tid] += t;
        __syncthreads();
    }
    if (i < N) offs[i] = tmp[tid] - v;          // block-local exclusive
    if (tid == 1023) bsums[blockIdx.x] = tmp[1023];
}

__global__ void k_scan2(int* bsums, int nb) {
    __shared__ int tmp[128];
    int tid = threadIdx.x;
    int v = (tid < nb) ? bsums[tid] : 0;
    tmp[tid] = v;
    __syncthreads();
    for (int d = 1; d < 128; d <<= 1) {
        int t = (tid >= d) ? tmp[tid - d] : 0;
        __syncthreads();
        tmp[tid] += t;
        __syncthreads();
    }
    if (tid < nb) bsums[tid] = tmp[tid] - v;    // exclusive block offsets
}

__global__ void k_scan3(int* __restrict__ offs, const int* __restrict__ bsums,
                        int* __restrict__ cursor, int N, int E) {
    int i = blockIdx.x * 1024 + threadIdx.x;
    if (i < N) {
        int o = offs[i] + bsums[blockIdx.x];
        offs[i] = o;
        cursor[i] = o;
    }
    if (i == 0) offs[N] = E;
}

__global__ void k_fill(const int* __restrict__ src, const int* __restrict__ dst,
                       int* __restrict__ cursor, int* __restrict__ col, int E) {
    int e = blockIdx.x * blockDim.x + threadIdx.x;
    if (e < E) {
        int p = atomicAdd(&cursor[dst[e]], 1);
        col[p] = src[e];
    }
}

// ---------------- GEMM: out[r][:] = (A[r][:] @ W) (+bias) (*scale[r]) ----------------

template <bool HAS_BIAS, bool SCALE>
__global__ void k_gemm64(const float* __restrict__ A, const float* __restrict__ W,
                         const float* __restrict__ bias, const float* __restrict__ scale,
                         float* __restrict__ out, int N) {
    __shared__ float Wl[64 * 64];
    int tid = threadIdx.x;
    {
        const float4* w4 = (const float4*)W;
        float4* wl4 = (float4*)Wl;
        for (int i = tid; i < 1024; i += 256) wl4[i] = w4[i];
    }
    __syncthreads();
    int r = blockIdx.x * 256 + tid;
    if (r >= N) return;

    float4 acc[16];
#pragma unroll
    for (int c4 = 0; c4 < 16; c4++) {
        if (HAS_BIAS) acc[c4] = ((const float4*)bias)[c4];
        else acc[c4] = make_float4(0.f, 0.f, 0.f, 0.f);
    }
    const float4* a4 = (const float4*)(A + (size_t)r * 64);
#pragma unroll 4
    for (int k4 = 0; k4 < 16; k4++) {
        float4 xv = a4[k4];
#pragma unroll
        for (int kk = 0; kk < 4; kk++) {
            float xk = (kk == 0) ? xv.x : (kk == 1) ? xv.y : (kk == 2) ? xv.z : xv.w;
            const float4* wr = (const float4*)(Wl + (k4 * 4 + kk) * 64);
#pragma unroll
            for (int c4 = 0; c4 < 16; c4++) {
                float4 w = wr[c4];
                acc[c4].x = fmaf(xk, w.x, acc[c4].x);
                acc[c4].y = fmaf(xk, w.y, acc[c4].y);
                acc[c4].z = fmaf(xk, w.z, acc[c4].z);
                acc[c4].w = fmaf(xk, w.w, acc[c4].w);
            }
        }
    }
    float s = SCALE ? scale[r] : 1.0f;
    float4* o4 = (float4*)(out + (size_t)r * 64);
#pragma unroll
    for (int c4 = 0; c4 < 16; c4++) {
        float4 v = acc[c4];
        if (SCALE) { v.x *= s; v.y *= s; v.z *= s; v.w *= s; }
        o4[c4] = v;
    }
}

// ---------------- Aggregation: h[d] = dinv[d]*(hw[d] + sum hw[src]) + bg + h[d] ----------------
// hw is pre-scaled by dinv[src]. One wave per node, lane = channel.

__global__ void k_agg(const float* __restrict__ hw, const int* __restrict__ offs,
                      const int* __restrict__ col, const float* __restrict__ dinv,
                      const float* __restrict__ bg, float* __restrict__ h, int N, int relu) {
    int t = blockIdx.x * blockDim.x + threadIdx.x;
    int node = t >> 6;
    int c = t & 63;
    if (node >= N) return;
    int start = offs[node];
    int end = offs[node + 1];
    float acc = hw[(size_t)node * 64 + c];  // self-loop term
    int e = start;
    for (; e + 4 <= end; e += 4) {
        int s0 = col[e], s1 = col[e + 1], s2 = col[e + 2], s3 = col[e + 3];
        float v0 = hw[(size_t)s0 * 64 + c];
        float v1 = hw[(size_t)s1 * 64 + c];
        float v2 = hw[(size_t)s2 * 64 + c];
        float v3 = hw[(size_t)s3 * 64 + c];
        acc += v0 + v1 + v2 + v3;
    }
    for (; e < end; ++e) acc += hw[(size_t)col[e] * 64 + c];
    float r = fmaf(dinv[node], acc, bg[c] + h[(size_t)node * 64 + c]);
    if (relu) r = fmaxf(r, 0.f);
    h[(size_t)node * 64 + c] = r;
}

// ---------------- Fused MLP readout: 64 -> 32 -> 16 -> 1 ----------------

__global__ void k_readout(const float* __restrict__ h,
                          const float* __restrict__ W0, const float* __restrict__ b0,
                          const float* __restrict__ W1, const float* __restrict__ b1,
                          const float* __restrict__ W2, const float* __restrict__ b2,
                          float* __restrict__ out, int N) {
    __shared__ float sW0[64 * 32];
    __shared__ float sW1[32 * 16];
    __shared__ float sW2[16];
    __shared__ float sb0[32], sb1[16];
    __shared__ float sb2v;
    int tid = threadIdx.x;
    for (int i = tid; i < 2048; i += 256) sW0[i] = W0[i];
    for (int i = tid; i < 512; i += 256) sW1[i] = W1[i];
    if (tid < 16) sW2[tid] = W2[tid];
    if (tid < 32) sb0[tid] = b0[tid];
    if (tid < 16) sb1[tid] = b1[tid];
    if (tid == 0) sb2v = b2[0];
    __syncthreads();
    int r = blockIdx.x * 256 + tid;
    if (r >= N) return;

    float hr[64];
    const float4* h4 = (const float4*)(h + (size_t)r * 64);
#pragma unroll
    for (int i = 0; i < 16; i++) {
        float4 v = h4[i];
        hr[i * 4] = v.x; hr[i * 4 + 1] = v.y; hr[i * 4 + 2] = v.z; hr[i * 4 + 3] = v.w;
    }
    float t0[32];
#pragma unroll 4
    for (int c = 0; c < 32; c++) {
        float a = sb0[c];
#pragma unroll
        for (int k = 0; k < 64; k++) a = fmaf(hr[k], sW0[k * 32 + c], a);
        t0[c] = fmaxf(a, 0.f);
    }
    float t1[16];
#pragma unroll 2
    for (int c = 0; c < 16; c++) {
        float a = sb1[c];
#pragma unroll
        for (int k = 0; k < 32; k++) a = fmaf(t0[k], sW1[k * 16 + c], a);
        t1[c] = fmaxf(a, 0.f);
    }
    float y = sb2v;
#pragma unroll
    for (int k = 0; k < 16; k++) y = fmaf(t1[k], sW2[k], y);
    out[r] = y;
}

// ---------------- launch ----------------

extern "C" void kernel_launch(void* const* d_in, const int* in_sizes, int n_in,
                              void* d_out, int out_size, void* d_ws, size_t ws_size,
                              hipStream_t stream) {
    const float* x     = (const float*)d_in[0];
    const int*   eidx  = (const int*)d_in[1];
    const float* W_enc = (const float*)d_in[2];
    const float* b_enc = (const float*)d_in[3];
    const float* Wg    = (const float*)d_in[4];
    const float* bg    = (const float*)d_in[5];
    const float* W0    = (const float*)d_in[6];
    const float* b0    = (const float*)d_in[7];
    const float* W1    = (const float*)d_in[8];
    const float* b1    = (const float*)d_in[9];
    const float* W2    = (const float*)d_in[10];
    const float* b2    = (const float*)d_in[11];

    int N = in_sizes[0] / 64;
    int E = in_sizes[1] / 2;
    const int* esrc = eidx;
    const int* edst = eidx + E;

    char* w = (char*)d_ws;
    auto alloc = [&](size_t bytes) -> char* {
        char* p = w;
        w += (bytes + 255) & ~(size_t)255;
        return p;
    };
    int*   cnt    = (int*)alloc((size_t)N * 4);
    int*   offs   = (int*)alloc((size_t)(N + 1) * 4);
    int*   cursor = (int*)alloc((size_t)N * 4);
    int*   bsums  = (int*)alloc(1024 * 4);
    int*   col    = (int*)alloc((size_t)E * 4);
    float* dinv   = (float*)alloc((size_t)N * 4);
    float* h      = (float*)alloc((size_t)N * 64 * 4);
    float* hw     = (float*)alloc((size_t)N * 64 * 4);

    hipMemsetAsync(cnt, 0, (size_t)N * 4, stream);

    const int TB = 256;
    k_count<<<(E + TB - 1) / TB, TB, 0, stream>>>(edst, cnt, E);
    k_dinv<<<(N + TB - 1) / TB, TB, 0, stream>>>(cnt, dinv, N);
    int nb = (N + 1023) / 1024;
    k_scan1<<<nb, 1024, 0, stream>>>(cnt, offs, bsums, N);
    k_scan2<<<1, 128, 0, stream>>>(bsums, nb);
    k_scan3<<<nb, 1024, 0, stream>>>(offs, bsums, cursor, N, E);
    k_fill<<<(E + TB - 1) / TB, TB, 0, stream>>>(esrc, edst, cursor, col, E);

    int gb = (N + 255) / 256;
    k_gemm64<true, false><<<gb, 256, 0, stream>>>(x, W_enc, b_enc, nullptr, h, N);
    for (int l = 0; l < 4; l++) {
        k_gemm64<false, true><<<gb, 256, 0, stream>>>(h, Wg + (size_t)l * 4096, nullptr, dinv, hw, N);
        k_agg<<<((size_t)N * 64 + 255) / 256, 256, 0, stream>>>(
            hw, offs, col, dinv, bg + (size_t)l * 64, h, N, (l != 3) ? 1 : 0);
    }
    k_readout<<<gb, 256, 0, stream>>>(h, W0, b0, W1, b1, W2, b2, (float*)d_out, N);
}

// Round 2
// 637.317 us; speedup vs baseline: 1.1778x; 1.1778x over previous
//
#include <hip/hip_runtime.h>

// ---------------- degree count ----------------

__global__ void k_count(const int* __restrict__ dst, int* __restrict__ cnt, int E) {
    int e = blockIdx.x * blockDim.x + threadIdx.x;
    if (e < E) atomicAdd(&cnt[dst[e]], 1);
}

// ---------------- hierarchical scan (+ dinv, + bucket cursors) ----------------

__global__ void k_scan1(const int* __restrict__ cnt, int* __restrict__ offs,
                        int* __restrict__ bsums, float* __restrict__ dinv, int N) {
    __shared__ int tmp[1024];
    int tid = threadIdx.x;
    int i = blockIdx.x * 1024 + tid;
    int v = (i < N) ? cnt[i] : 0;
    if (i < N) dinv[i] = rsqrtf((float)(v + 1));  // +1 self-loop
    tmp[tid] = v;
    __syncthreads();
    for (int d = 1; d < 1024; d <<= 1) {
        int t = (tid >= d) ? tmp[tid - d] : 0;
        __syncthreads();
        tmp[tid] += t;
        __syncthreads();
    }
    if (i < N) offs[i] = tmp[tid] - v;          // block-local exclusive
    if (tid == 1023) bsums[blockIdx.x] = tmp[1023];
}

__global__ void k_scan2(int* bsums, int nb) {
    __shared__ int tmp[128];
    int tid = threadIdx.x;
    int v = (tid < nb) ? bsums[tid] : 0;
    tmp[tid] = v;
    __syncthreads();
    for (int d = 1; d < 128; d <<= 1) {
        int t = (tid >= d) ? tmp[tid - d] : 0;
        __syncthreads();
        tmp[tid] += t;
        __syncthreads();
    }
    if (tid < nb) bsums[tid] = tmp[tid] - v;    // exclusive block offsets
}

__global__ void k_scan3(int* __restrict__ offs, const int* __restrict__ bsums,
                        int* __restrict__ bcur, int N, int E) {
    int i = blockIdx.x * 1024 + threadIdx.x;
    if (i < N) {
        int o = offs[i] + bsums[blockIdx.x];
        offs[i] = o;
        if ((i & 255) == 0) bcur[i >> 8] = o;   // bucket region cursor = CSR base
    }
    if (i == 0) offs[N] = E;
}

// ---------------- partition: edges -> 391 coarse buckets (256 nodes each) ----------------
// Output bpk[]: packed (dst_local<<17)|src, grouped by bucket (region = CSR range).

#define PCHUNK 8192
#define PTHREADS 512
#define NBUCK_MAX 400

__global__ __launch_bounds__(PTHREADS)
void k_partition(const int* __restrict__ src, const int* __restrict__ dst,
                 int* __restrict__ bcur, unsigned int* __restrict__ bpk,
                 int E, int nbuck) {
    __shared__ int hist[NBUCK_MAX];
    __shared__ int boffs[NBUCK_MAX];
    __shared__ int cur[NBUCK_MAX];
    __shared__ int gbase[NBUCK_MAX];
    __shared__ int tmp[PTHREADS];
    __shared__ unsigned int stage[PCHUNK];
    __shared__ unsigned short sbid[PCHUNK];

    int tid = threadIdx.x;
    int ebase = blockIdx.x * PCHUNK;
    int ecount = min(PCHUNK, E - ebase);

    if (tid < NBUCK_MAX) hist[tid] = 0;
    __syncthreads();

    int dreg[16], sreg[16];
#pragma unroll
    for (int k = 0; k < 16; k++) {
        int e = ebase + tid + k * PTHREADS;
        if (tid + k * PTHREADS < ecount) {
            dreg[k] = dst[e];
            sreg[k] = src[e];
            atomicAdd(&hist[dreg[k] >> 8], 1);
        } else dreg[k] = -1;
    }
    __syncthreads();

    // exclusive scan of hist[0..nbuck) via Hillis-Steele on PTHREADS
    int v = (tid < nbuck) ? hist[tid] : 0;
    tmp[tid] = v;
    __syncthreads();
    for (int d = 1; d < PTHREADS; d <<= 1) {
        int t = (tid >= d) ? tmp[tid - d] : 0;
        __syncthreads();
        tmp[tid] += t;
        __syncthreads();
    }
    if (tid < nbuck) { boffs[tid] = tmp[tid] - v; cur[tid] = tmp[tid] - v; }
    __syncthreads();

    // scatter into LDS staging, grouped by bucket
#pragma unroll
    for (int k = 0; k < 16; k++) {
        if (dreg[k] >= 0) {
            int b = dreg[k] >> 8;
            int p = atomicAdd(&cur[b], 1);
            stage[p] = ((unsigned int)(dreg[k] & 255) << 17) | (unsigned int)sreg[k];
            sbid[p] = (unsigned short)b;
        }
    }
    __syncthreads();

    // reserve global space per present bucket
    if (tid < nbuck) {
        int c = cur[tid] - boffs[tid];
        if (c > 0) gbase[tid] = atomicAdd(&bcur[tid], c);
    }
    __syncthreads();

    // coalesced-ish flush (runs of same bucket are contiguous)
    for (int i = tid; i < ecount; i += PTHREADS) {
        int b = sbid[i];
        bpk[gbase[b] + (i - boffs[b])] = stage[i];
    }
}

// ---------------- fine fill: bucket-grouped -> exact per-node CSR col[] ----------------

#define FCAP 6144

__global__ __launch_bounds__(1024)
void k_finefill(const unsigned int* __restrict__ bpk, const int* __restrict__ offs,
                int* __restrict__ col, int N) {
    __shared__ int cur[256];
    __shared__ unsigned int stage[FCAP];
    int b = blockIdx.x;
    int tid = threadIdx.x;
    int nbase = b << 8;
    int nend = min(nbase + 256, N);
    int nn = nend - nbase;
    int base = offs[nbase];
    int bedges = offs[nend] - base;

    if (tid < nn) cur[tid] = offs[nbase + tid] - base;
    __syncthreads();

    if (bedges <= FCAP) {
        for (int i = tid; i < bedges; i += 1024) {
            unsigned int v = bpk[base + i];
            int dl = v >> 17;
            int p = atomicAdd(&cur[dl], 1);
            stage[p] = v & 0x1FFFFu;
        }
        __syncthreads();
        for (int i = tid; i < bedges; i += 1024)
            col[base + i] = (int)stage[i];
    } else {
        // deterministic fallback (never expected at these sizes)
        for (int i = tid; i < bedges; i += 1024) {
            unsigned int v = bpk[base + i];
            int dl = v >> 17;
            int p = atomicAdd(&cur[dl], 1);
            col[base + p] = (int)(v & 0x1FFFFu);
        }
    }
}

// ---------------- GEMM: out[r][:] = (A[r][:] @ W) (+bias) (*scale[r]) ----------------

template <bool HAS_BIAS, bool SCALE>
__global__ void k_gemm64(const float* __restrict__ A, const float* __restrict__ W,
                         const float* __restrict__ bias, const float* __restrict__ scale,
                         float* __restrict__ out, int N) {
    __shared__ float Wl[64 * 64];
    int tid = threadIdx.x;
    {
        const float4* w4 = (const float4*)W;
        float4* wl4 = (float4*)Wl;
        for (int i = tid; i < 1024; i += 256) wl4[i] = w4[i];
    }
    __syncthreads();
    int r = blockIdx.x * 256 + tid;
    if (r >= N) return;

    float4 acc[16];
#pragma unroll
    for (int c4 = 0; c4 < 16; c4++) {
        if (HAS_BIAS) acc[c4] = ((const float4*)bias)[c4];
        else acc[c4] = make_float4(0.f, 0.f, 0.f, 0.f);
    }
    const float4* a4 = (const float4*)(A + (size_t)r * 64);
#pragma unroll 4
    for (int k4 = 0; k4 < 16; k4++) {
        float4 xv = a4[k4];
#pragma unroll
        for (int kk = 0; kk < 4; kk++) {
            float xk = (kk == 0) ? xv.x : (kk == 1) ? xv.y : (kk == 2) ? xv.z : xv.w;
            const float4* wr = (const float4*)(Wl + (k4 * 4 + kk) * 64);
#pragma unroll
            for (int c4 = 0; c4 < 16; c4++) {
                float4 w = wr[c4];
                acc[c4].x = fmaf(xk, w.x, acc[c4].x);
                acc[c4].y = fmaf(xk, w.y, acc[c4].y);
                acc[c4].z = fmaf(xk, w.z, acc[c4].z);
                acc[c4].w = fmaf(xk, w.w, acc[c4].w);
            }
        }
    }
    float s = SCALE ? scale[r] : 1.0f;
    float4* o4 = (float4*)(out + (size_t)r * 64);
#pragma unroll
    for (int c4 = 0; c4 < 16; c4++) {
        float4 v = acc[c4];
        if (SCALE) { v.x *= s; v.y *= s; v.z *= s; v.w *= s; }
        o4[c4] = v;
    }
}

// ---------------- Aggregation: h[d] = dinv[d]*(hw[d] + sum hw[src]) + bg + h[d] ----------------

__global__ void k_agg(const float* __restrict__ hw, const int* __restrict__ offs,
                      const int* __restrict__ col, const float* __restrict__ dinv,
                      const float* __restrict__ bg, float* __restrict__ h, int N, int relu) {
    int t = blockIdx.x * blockDim.x + threadIdx.x;
    int node = t >> 6;
    int c = t & 63;
    if (node >= N) return;
    int start = offs[node];
    int end = offs[node + 1];
    float acc = hw[(size_t)node * 64 + c];  // self-loop term
    int e = start;
    for (; e + 4 <= end; e += 4) {
        int s0 = col[e], s1 = col[e + 1], s2 = col[e + 2], s3 = col[e + 3];
        float v0 = hw[(size_t)s0 * 64 + c];
        float v1 = hw[(size_t)s1 * 64 + c];
        float v2 = hw[(size_t)s2 * 64 + c];
        float v3 = hw[(size_t)s3 * 64 + c];
        acc += v0 + v1 + v2 + v3;
    }
    for (; e < end; ++e) acc += hw[(size_t)col[e] * 64 + c];
    float r = fmaf(dinv[node], acc, bg[c] + h[(size_t)node * 64 + c]);
    if (relu) r = fmaxf(r, 0.f);
    h[(size_t)node * 64 + c] = r;
}

// ---------------- Fused MLP readout: 64 -> 32 -> 16 -> 1 ----------------

__global__ void k_readout(const float* __restrict__ h,
                          const float* __restrict__ W0, const float* __restrict__ b0,
                          const float* __restrict__ W1, const float* __restrict__ b1,
                          const float* __restrict__ W2, const float* __restrict__ b2,
                          float* __restrict__ out, int N) {
    __shared__ float sW0[64 * 32];
    __shared__ float sW1[32 * 16];
    __shared__ float sW2[16];
    __shared__ float sb0[32], sb1[16];
    __shared__ float sb2v;
    int tid = threadIdx.x;
    for (int i = tid; i < 2048; i += 256) sW0[i] = W0[i];
    for (int i = tid; i < 512; i += 256) sW1[i] = W1[i];
    if (tid < 16) sW2[tid] = W2[tid];
    if (tid < 32) sb0[tid] = b0[tid];
    if (tid < 16) sb1[tid] = b1[tid];
    if (tid == 0) sb2v = b2[0];
    __syncthreads();
    int r = blockIdx.x * 256 + tid;
    if (r >= N) return;

    float hr[64];
    const float4* h4 = (const float4*)(h + (size_t)r * 64);
#pragma unroll
    for (int i = 0; i < 16; i++) {
        float4 v = h4[i];
        hr[i * 4] = v.x; hr[i * 4 + 1] = v.y; hr[i * 4 + 2] = v.z; hr[i * 4 + 3] = v.w;
    }
    float t0[32];
#pragma unroll 4
    for (int c = 0; c < 32; c++) {
        float a = sb0[c];
#pragma unroll
        for (int k = 0; k < 64; k++) a = fmaf(hr[k], sW0[k * 32 + c], a);
        t0[c] = fmaxf(a, 0.f);
    }
    float t1[16];
#pragma unroll 2
    for (int c = 0; c < 16; c++) {
        float a = sb1[c];
#pragma unroll
        for (int k = 0; k < 32; k++) a = fmaf(t0[k], sW1[k * 16 + c], a);
        t1[c] = fmaxf(a, 0.f);
    }
    float y = sb2v;
#pragma unroll
    for (int k = 0; k < 16; k++) y = fmaf(t1[k], sW2[k], y);
    out[r] = y;
}

// ---------------- launch ----------------

extern "C" void kernel_launch(void* const* d_in, const int* in_sizes, int n_in,
                              void* d_out, int out_size, void* d_ws, size_t ws_size,
                              hipStream_t stream) {
    const float* x     = (const float*)d_in[0];
    const int*   eidx  = (const int*)d_in[1];
    const float* W_enc = (const float*)d_in[2];
    const float* b_enc = (const float*)d_in[3];
    const float* Wg    = (const float*)d_in[4];
    const float* bg    = (const float*)d_in[5];
    const float* W0    = (const float*)d_in[6];
    const float* b0    = (const float*)d_in[7];
    const float* W1    = (const float*)d_in[8];
    const float* b1    = (const float*)d_in[9];
    const float* W2    = (const float*)d_in[10];
    const float* b2    = (const float*)d_in[11];

    int N = in_sizes[0] / 64;
    int E = in_sizes[1] / 2;
    const int* esrc = eidx;
    const int* edst = eidx + E;
    int nbuck = (N + 255) >> 8;

    char* w = (char*)d_ws;
    auto alloc = [&](size_t bytes) -> char* {
        char* p = w;
        w += (bytes + 255) & ~(size_t)255;
        return p;
    };
    int*   cnt  = (int*)alloc((size_t)N * 4);
    int*   offs = (int*)alloc((size_t)(N + 1) * 4);
    int*   bcur = (int*)alloc(512 * 4);
    int*   bsums = (int*)alloc(1024 * 4);
    int*   col  = (int*)alloc((size_t)E * 4);
    unsigned int* bpk = (unsigned int*)alloc((size_t)E * 4);
    float* dinv = (float*)alloc((size_t)N * 4);
    float* h    = (float*)alloc((size_t)N * 64 * 4);
    float* hw   = (float*)alloc((size_t)N * 64 * 4);

    hipMemsetAsync(cnt, 0, (size_t)N * 4, stream);

    const int TB = 256;
    k_count<<<(E + TB - 1) / TB, TB, 0, stream>>>(edst, cnt, E);
    int nb = (N + 1023) / 1024;
    k_scan1<<<nb, 1024, 0, stream>>>(cnt, offs, bsums, dinv, N);
    k_scan2<<<1, 128, 0, stream>>>(bsums, nb);
    k_scan3<<<nb, 1024, 0, stream>>>(offs, bsums, bcur, N, E);
    k_partition<<<(E + PCHUNK - 1) / PCHUNK, PTHREADS, 0, stream>>>(esrc, edst, bcur, bpk, E, nbuck);
    k_finefill<<<nbuck, 1024, 0, stream>>>(bpk, offs, col, N);

    int gb = (N + 255) / 256;
    k_gemm64<true, false><<<gb, 256, 0, stream>>>(x, W_enc, b_enc, nullptr, h, N);
    for (int l = 0; l < 4; l++) {
        k_gemm64<false, true><<<gb, 256, 0, stream>>>(h, Wg + (size_t)l * 4096, nullptr, dinv, hw, N);
        k_agg<<<((size_t)N * 64 + 255) / 256, 256, 0, stream>>>(
            hw, offs, col, dinv, bg + (size_t)l * 64, h, N, (l != 3) ? 1 : 0);
    }
    k_readout<<<gb, 256, 0, stream>>>(h, W0, b0, W1, b1, W2, b2, (float*)d_out, N);
}

// Round 3
// 586.406 us; speedup vs baseline: 1.2800x; 1.0868x over previous
//
#include <hip/hip_runtime.h>

// ---------------- degree count ----------------

__global__ void k_count(const int* __restrict__ dst, int* __restrict__ cnt, int E) {
    int e = blockIdx.x * blockDim.x + threadIdx.x;
    if (e < E) atomicAdd(&cnt[dst[e]], 1);
}

// ---------------- hierarchical scan (+ dinv, + bucket cursors) ----------------

__global__ void k_scan1(const int* __restrict__ cnt, int* __restrict__ offs,
                        int* __restrict__ bsums, float* __restrict__ dinv, int N) {
    __shared__ int tmp[1024];
    int tid = threadIdx.x;
    int i = blockIdx.x * 1024 + tid;
    int v = (i < N) ? cnt[i] : 0;
    if (i < N) dinv[i] = rsqrtf((float)(v + 1));  // +1 self-loop
    tmp[tid] = v;
    __syncthreads();
    for (int d = 1; d < 1024; d <<= 1) {
        int t = (tid >= d) ? tmp[tid - d] : 0;
        __syncthreads();
        tmp[tid] += t;
        __syncthreads();
    }
    if (i < N) offs[i] = tmp[tid] - v;          // block-local exclusive
    if (tid == 1023) bsums[blockIdx.x] = tmp[1023];
}

__global__ void k_scan2(int* bsums, int nb) {
    __shared__ int tmp[128];
    int tid = threadIdx.x;
    int v = (tid < nb) ? bsums[tid] : 0;
    tmp[tid] = v;
    __syncthreads();
    for (int d = 1; d < 128; d <<= 1) {
        int t = (tid >= d) ? tmp[tid - d] : 0;
        __syncthreads();
        tmp[tid] += t;
        __syncthreads();
    }
    if (tid < nb) bsums[tid] = tmp[tid] - v;    // exclusive block offsets
}

__global__ void k_scan3(int* __restrict__ offs, const int* __restrict__ bsums,
                        int* __restrict__ bcur, int N, int E) {
    int i = blockIdx.x * 1024 + threadIdx.x;
    if (i < N) {
        int o = offs[i] + bsums[blockIdx.x];
        offs[i] = o;
        if ((i & 255) == 0) bcur[i >> 8] = o;   // bucket region cursor = CSR base
    }
    if (i == 0) offs[N] = E;
}

// ---------------- partition: edges -> coarse buckets (256 nodes each) ----------------

#define PCHUNK 8192
#define PTHREADS 512
#define NBUCK_MAX 400

__global__ __launch_bounds__(PTHREADS)
void k_partition(const int* __restrict__ src, const int* __restrict__ dst,
                 int* __restrict__ bcur, unsigned int* __restrict__ bpk,
                 int E, int nbuck) {
    __shared__ int hist[NBUCK_MAX];
    __shared__ int boffs[NBUCK_MAX];
    __shared__ int cur[NBUCK_MAX];
    __shared__ int gbase[NBUCK_MAX];
    __shared__ int tmp[PTHREADS];
    __shared__ unsigned int stage[PCHUNK];
    __shared__ unsigned short sbid[PCHUNK];

    int tid = threadIdx.x;
    int ebase = blockIdx.x * PCHUNK;
    int ecount = min(PCHUNK, E - ebase);

    if (tid < NBUCK_MAX) hist[tid] = 0;
    __syncthreads();

    int dreg[16], sreg[16];
#pragma unroll
    for (int k = 0; k < 16; k++) {
        int e = ebase + tid + k * PTHREADS;
        if (tid + k * PTHREADS < ecount) {
            dreg[k] = dst[e];
            sreg[k] = src[e];
            atomicAdd(&hist[dreg[k] >> 8], 1);
        } else dreg[k] = -1;
    }
    __syncthreads();

    int v = (tid < nbuck) ? hist[tid] : 0;
    tmp[tid] = v;
    __syncthreads();
    for (int d = 1; d < PTHREADS; d <<= 1) {
        int t = (tid >= d) ? tmp[tid - d] : 0;
        __syncthreads();
        tmp[tid] += t;
        __syncthreads();
    }
    if (tid < nbuck) { boffs[tid] = tmp[tid] - v; cur[tid] = tmp[tid] - v; }
    __syncthreads();

#pragma unroll
    for (int k = 0; k < 16; k++) {
        if (dreg[k] >= 0) {
            int b = dreg[k] >> 8;
            int p = atomicAdd(&cur[b], 1);
            stage[p] = ((unsigned int)(dreg[k] & 255) << 17) | (unsigned int)sreg[k];
            sbid[p] = (unsigned short)b;
        }
    }
    __syncthreads();

    if (tid < nbuck) {
        int c = cur[tid] - boffs[tid];
        if (c > 0) gbase[tid] = atomicAdd(&bcur[tid], c);
    }
    __syncthreads();

    for (int i = tid; i < ecount; i += PTHREADS) {
        int b = sbid[i];
        bpk[gbase[b] + (i - boffs[b])] = stage[i];
    }
}

// ---------------- fine fill: bucket-grouped -> exact per-node CSR col[] ----------------

#define FCAP 6144

__global__ __launch_bounds__(1024)
void k_finefill(const unsigned int* __restrict__ bpk, const int* __restrict__ offs,
                int* __restrict__ col, int N) {
    __shared__ int cur[256];
    __shared__ unsigned int stage[FCAP];
    int b = blockIdx.x;
    int tid = threadIdx.x;
    int nbase = b << 8;
    int nend = min(nbase + 256, N);
    int nn = nend - nbase;
    int base = offs[nbase];
    int bedges = offs[nend] - base;

    if (tid < nn) cur[tid] = offs[nbase + tid] - base;
    __syncthreads();

    if (bedges <= FCAP) {
        for (int i = tid; i < bedges; i += 1024) {
            unsigned int v = bpk[base + i];
            int dl = v >> 17;
            int p = atomicAdd(&cur[dl], 1);
            stage[p] = v & 0x1FFFFu;
        }
        __syncthreads();
        for (int i = tid; i < bedges; i += 1024)
            col[base + i] = (int)stage[i];
    } else {
        for (int i = tid; i < bedges; i += 1024) {
            unsigned int v = bpk[base + i];
            int dl = v >> 17;
            int p = atomicAdd(&cur[dl], 1);
            col[base + p] = (int)(v & 0x1FFFFu);
        }
    }
}

// ---------------- GEMM: out[r][:] = (A[r][:] @ W) (+bias) (*scale[r]) ----------------

template <bool HAS_BIAS, bool SCALE>
__global__ void k_gemm64(const float* __restrict__ A, const float* __restrict__ W,
                         const float* __restrict__ bias, const float* __restrict__ scale,
                         float* __restrict__ out, int N) {
    __shared__ float Wl[64 * 64];
    int tid = threadIdx.x;
    {
        const float4* w4 = (const float4*)W;
        float4* wl4 = (float4*)Wl;
        for (int i = tid; i < 1024; i += 256) wl4[i] = w4[i];
    }
    __syncthreads();
    int r = blockIdx.x * 256 + tid;
    if (r >= N) return;

    float4 acc[16];
#pragma unroll
    for (int c4 = 0; c4 < 16; c4++) {
        if (HAS_BIAS) acc[c4] = ((const float4*)bias)[c4];
        else acc[c4] = make_float4(0.f, 0.f, 0.f, 0.f);
    }
    const float4* a4 = (const float4*)(A + (size_t)r * 64);
#pragma unroll 4
    for (int k4 = 0; k4 < 16; k4++) {
        float4 xv = a4[k4];
#pragma unroll
        for (int kk = 0; kk < 4; kk++) {
            float xk = (kk == 0) ? xv.x : (kk == 1) ? xv.y : (kk == 2) ? xv.z : xv.w;
            const float4* wr = (const float4*)(Wl + (k4 * 4 + kk) * 64);
#pragma unroll
            for (int c4 = 0; c4 < 16; c4++) {
                float4 w = wr[c4];
                acc[c4].x = fmaf(xk, w.x, acc[c4].x);
                acc[c4].y = fmaf(xk, w.y, acc[c4].y);
                acc[c4].z = fmaf(xk, w.z, acc[c4].z);
                acc[c4].w = fmaf(xk, w.w, acc[c4].w);
            }
        }
    }
    float s = SCALE ? scale[r] : 1.0f;
    float4* o4 = (float4*)(out + (size_t)r * 64);
#pragma unroll
    for (int c4 = 0; c4 < 16; c4++) {
        float4 v = acc[c4];
        if (SCALE) { v.x *= s; v.y *= s; v.z *= s; v.w *= s; }
        o4[c4] = v;
    }
}

// ---------------- Aggregation: h[d] = dinv[d]*(hw[d] + sum hw[src]) + bg + h[d] ----------------

__global__ void k_agg(const float* __restrict__ hw, const int* __restrict__ offs,
                      const int* __restrict__ col, const float* __restrict__ dinv,
                      const float* __restrict__ bg, float* __restrict__ h, int N, int relu) {
    int t = blockIdx.x * blockDim.x + threadIdx.x;
    int node = t >> 6;
    int c = t & 63;
    if (node >= N) return;
    int start = offs[node];
    int end = offs[node + 1];
    float acc = hw[(size_t)node * 64 + c];  // self-loop term
    int e = start;
    for (; e + 4 <= end; e += 4) {
        int s0 = col[e], s1 = col[e + 1], s2 = col[e + 2], s3 = col[e + 3];
        float v0 = hw[(size_t)s0 * 64 + c];
        float v1 = hw[(size_t)s1 * 64 + c];
        float v2 = hw[(size_t)s2 * 64 + c];
        float v3 = hw[(size_t)s3 * 64 + c];
        acc += v0 + v1 + v2 + v3;
    }
    for (; e < end; ++e) acc += hw[(size_t)col[e] * 64 + c];
    float r = fmaf(dinv[node], acc, bg[c] + h[(size_t)node * 64 + c]);
    if (relu) r = fmaxf(r, 0.f);
    h[(size_t)node * 64 + c] = r;
}

// ---------------- Fused MLP readout: 64 -> 32 -> 16 -> 1 ----------------
// All loops FULLY unrolled: every t0[]/t1[] index is compile-time (no scratch,
// rule #20). Weights read directly from global with wave-uniform static-offset
// addresses -> compiler emits s_load (scalar cache broadcast); VALU stays pure
// v_fmac. No LDS needed at all.

__global__ __launch_bounds__(256)
void k_readout(const float* __restrict__ h,
               const float* __restrict__ W0, const float* __restrict__ b0,
               const float* __restrict__ W1, const float* __restrict__ b1,
               const float* __restrict__ W2, const float* __restrict__ b2,
               float* __restrict__ out, int N) {
    int r = blockIdx.x * 256 + threadIdx.x;
    if (r >= N) return;

    float t0[32];
#pragma unroll
    for (int c = 0; c < 32; c++) t0[c] = b0[c];

    const float4* h4 = (const float4*)(h + (size_t)r * 64);
#pragma unroll
    for (int k4 = 0; k4 < 16; k4++) {
        float4 v = h4[k4];
#pragma unroll
        for (int kk = 0; kk < 4; kk++) {
            float xk = (kk == 0) ? v.x : (kk == 1) ? v.y : (kk == 2) ? v.z : v.w;
            const float* wr = W0 + (k4 * 4 + kk) * 32;
#pragma unroll
            for (int c = 0; c < 32; c++) t0[c] = fmaf(xk, wr[c], t0[c]);
        }
    }
#pragma unroll
    for (int c = 0; c < 32; c++) t0[c] = fmaxf(t0[c], 0.f);

    float t1[16];
#pragma unroll
    for (int c = 0; c < 16; c++) t1[c] = b1[c];
#pragma unroll
    for (int k = 0; k < 32; k++) {
        const float* wr = W1 + k * 16;
#pragma unroll
        for (int c = 0; c < 16; c++) t1[c] = fmaf(t0[k], wr[c], t1[c]);
    }
#pragma unroll
    for (int c = 0; c < 16; c++) t1[c] = fmaxf(t1[c], 0.f);

    float y = b2[0];
#pragma unroll
    for (int k = 0; k < 16; k++) y = fmaf(t1[k], W2[k], y);
    out[r] = y;
}

// ---------------- launch ----------------

extern "C" void kernel_launch(void* const* d_in, const int* in_sizes, int n_in,
                              void* d_out, int out_size, void* d_ws, size_t ws_size,
                              hipStream_t stream) {
    const float* x     = (const float*)d_in[0];
    const int*   eidx  = (const int*)d_in[1];
    const float* W_enc = (const float*)d_in[2];
    const float* b_enc = (const float*)d_in[3];
    const float* Wg    = (const float*)d_in[4];
    const float* bg    = (const float*)d_in[5];
    const float* W0    = (const float*)d_in[6];
    const float* b0    = (const float*)d_in[7];
    const float* W1    = (const float*)d_in[8];
    const float* b1    = (const float*)d_in[9];
    const float* W2    = (const float*)d_in[10];
    const float* b2    = (const float*)d_in[11];

    int N = in_sizes[0] / 64;
    int E = in_sizes[1] / 2;
    const int* esrc = eidx;
    const int* edst = eidx + E;
    int nbuck = (N + 255) >> 8;

    char* w = (char*)d_ws;
    auto alloc = [&](size_t bytes) -> char* {
        char* p = w;
        w += (bytes + 255) & ~(size_t)255;
        return p;
    };
    int*   cnt  = (int*)alloc((size_t)N * 4);
    int*   offs = (int*)alloc((size_t)(N + 1) * 4);
    int*   bcur = (int*)alloc(512 * 4);
    int*   bsums = (int*)alloc(1024 * 4);
    int*   col  = (int*)alloc((size_t)E * 4);
    unsigned int* bpk = (unsigned int*)alloc((size_t)E * 4);
    float* dinv = (float*)alloc((size_t)N * 4);
    float* h    = (float*)alloc((size_t)N * 64 * 4);
    float* hw   = (float*)alloc((size_t)N * 64 * 4);

    hipMemsetAsync(cnt, 0, (size_t)N * 4, stream);

    const int TB = 256;
    k_count<<<(E + TB - 1) / TB, TB, 0, stream>>>(edst, cnt, E);
    int nb = (N + 1023) / 1024;
    k_scan1<<<nb, 1024, 0, stream>>>(cnt, offs, bsums, dinv, N);
    k_scan2<<<1, 128, 0, stream>>>(bsums, nb);
    k_scan3<<<nb, 1024, 0, stream>>>(offs, bsums, bcur, N, E);
    k_partition<<<(E + PCHUNK - 1) / PCHUNK, PTHREADS, 0, stream>>>(esrc, edst, bcur, bpk, E, nbuck);
    k_finefill<<<nbuck, 1024, 0, stream>>>(bpk, offs, col, N);

    int gb = (N + 255) / 256;
    k_gemm64<true, false><<<gb, 256, 0, stream>>>(x, W_enc, b_enc, nullptr, h, N);
    for (int l = 0; l < 4; l++) {
        k_gemm64<false, true><<<gb, 256, 0, stream>>>(h, Wg + (size_t)l * 4096, nullptr, dinv, hw, N);
        k_agg<<<((size_t)N * 64 + 255) / 256, 256, 0, stream>>>(
            hw, offs, col, dinv, bg + (size_t)l * 64, h, N, (l != 3) ? 1 : 0);
    }
    k_readout<<<gb, 256, 0, stream>>>(h, W0, b0, W1, b1, W2, b2, (float*)d_out, N);
}

// Round 4
// 565.151 us; speedup vs baseline: 1.3281x; 1.0376x over previous
//
#include <hip/hip_runtime.h>

// ---------------- degree count ----------------

__global__ void k_count(const int* __restrict__ dst, int* __restrict__ cnt, int E) {
    int e = blockIdx.x * blockDim.x + threadIdx.x;
    if (e < E) atomicAdd(&cnt[dst[e]], 1);
}

// ---------------- hierarchical scan (+ dinv, + bucket cursors) ----------------

__global__ void k_scan1(const int* __restrict__ cnt, int* __restrict__ offs,
                        int* __restrict__ bsums, float* __restrict__ dinv, int N) {
    __shared__ int tmp[1024];
    int tid = threadIdx.x;
    int i = blockIdx.x * 1024 + tid;
    int v = (i < N) ? cnt[i] : 0;
    if (i < N) dinv[i] = rsqrtf((float)(v + 1));  // +1 self-loop
    tmp[tid] = v;
    __syncthreads();
    for (int d = 1; d < 1024; d <<= 1) {
        int t = (tid >= d) ? tmp[tid - d] : 0;
        __syncthreads();
        tmp[tid] += t;
        __syncthreads();
    }
    if (i < N) offs[i] = tmp[tid] - v;          // block-local exclusive
    if (tid == 1023) bsums[blockIdx.x] = tmp[1023];
}

__global__ void k_scan2(int* bsums, int nb) {
    __shared__ int tmp[128];
    int tid = threadIdx.x;
    int v = (tid < nb) ? bsums[tid] : 0;
    tmp[tid] = v;
    __syncthreads();
    for (int d = 1; d < 128; d <<= 1) {
        int t = (tid >= d) ? tmp[tid - d] : 0;
        __syncthreads();
        tmp[tid] += t;
        __syncthreads();
    }
    if (tid < nb) bsums[tid] = tmp[tid] - v;    // exclusive block offsets
}

__global__ void k_scan3(int* __restrict__ offs, const int* __restrict__ bsums,
                        int* __restrict__ bcur, int N, int E) {
    int i = blockIdx.x * 1024 + threadIdx.x;
    if (i < N) {
        int o = offs[i] + bsums[blockIdx.x];
        offs[i] = o;
        if ((i & 255) == 0) bcur[i >> 8] = o;   // bucket region cursor = CSR base
    }
    if (i == 0) offs[N] = E;
}

// ---------------- partition: edges -> coarse buckets (256 nodes each) ----------------

#define PCHUNK 8192
#define PTHREADS 512
#define NBUCK_MAX 400

__global__ __launch_bounds__(PTHREADS)
void k_partition(const int* __restrict__ src, const int* __restrict__ dst,
                 int* __restrict__ bcur, unsigned int* __restrict__ bpk,
                 int E, int nbuck) {
    __shared__ int hist[NBUCK_MAX];
    __shared__ int boffs[NBUCK_MAX];
    __shared__ int cur[NBUCK_MAX];
    __shared__ int gbase[NBUCK_MAX];
    __shared__ int tmp[PTHREADS];
    __shared__ unsigned int stage[PCHUNK];
    __shared__ unsigned short sbid[PCHUNK];

    int tid = threadIdx.x;
    int ebase = blockIdx.x * PCHUNK;
    int ecount = min(PCHUNK, E - ebase);

    if (tid < NBUCK_MAX) hist[tid] = 0;
    __syncthreads();

    int dreg[16], sreg[16];
#pragma unroll
    for (int k = 0; k < 16; k++) {
        int e = ebase + tid + k * PTHREADS;
        if (tid + k * PTHREADS < ecount) {
            dreg[k] = dst[e];
            sreg[k] = src[e];
            atomicAdd(&hist[dreg[k] >> 8], 1);
        } else dreg[k] = -1;
    }
    __syncthreads();

    int v = (tid < nbuck) ? hist[tid] : 0;
    tmp[tid] = v;
    __syncthreads();
    for (int d = 1; d < PTHREADS; d <<= 1) {
        int t = (tid >= d) ? tmp[tid - d] : 0;
        __syncthreads();
        tmp[tid] += t;
        __syncthreads();
    }
    if (tid < nbuck) { boffs[tid] = tmp[tid] - v; cur[tid] = tmp[tid] - v; }
    __syncthreads();

#pragma unroll
    for (int k = 0; k < 16; k++) {
        if (dreg[k] >= 0) {
            int b = dreg[k] >> 8;
            int p = atomicAdd(&cur[b], 1);
            stage[p] = ((unsigned int)(dreg[k] & 255) << 17) | (unsigned int)sreg[k];
            sbid[p] = (unsigned short)b;
        }
    }
    __syncthreads();

    if (tid < nbuck) {
        int c = cur[tid] - boffs[tid];
        if (c > 0) gbase[tid] = atomicAdd(&bcur[tid], c);
    }
    __syncthreads();

    for (int i = tid; i < ecount; i += PTHREADS) {
        int b = sbid[i];
        bpk[gbase[b] + (i - boffs[b])] = stage[i];
    }
}

// ---------------- fine fill: bucket-grouped -> exact per-node CSR col[] ----------------

#define FCAP 6144

__global__ __launch_bounds__(1024)
void k_finefill(const unsigned int* __restrict__ bpk, const int* __restrict__ offs,
                int* __restrict__ col, int N) {
    __shared__ int cur[256];
    __shared__ unsigned int stage[FCAP];
    int b = blockIdx.x;
    int tid = threadIdx.x;
    int nbase = b << 8;
    int nend = min(nbase + 256, N);
    int nn = nend - nbase;
    int base = offs[nbase];
    int bedges = offs[nend] - base;

    if (tid < nn) cur[tid] = offs[nbase + tid] - base;
    __syncthreads();

    if (bedges <= FCAP) {
        for (int i = tid; i < bedges; i += 1024) {
            unsigned int v = bpk[base + i];
            int dl = v >> 17;
            int p = atomicAdd(&cur[dl], 1);
            stage[p] = v & 0x1FFFFu;
        }
        __syncthreads();
        for (int i = tid; i < bedges; i += 1024)
            col[base + i] = (int)stage[i];
    } else {
        for (int i = tid; i < bedges; i += 1024) {
            unsigned int v = bpk[base + i];
            int dl = v >> 17;
            int p = atomicAdd(&cur[dl], 1);
            col[base + p] = (int)(v & 0x1FFFFu);
        }
    }
}

// ---------------- bf16 helpers ----------------

__device__ __forceinline__ unsigned int bf16rne(float x) {
    unsigned int u = __float_as_uint(x);
    return (u + 0x7FFFu + ((u >> 16) & 1u)) >> 16;
}
__device__ __forceinline__ float bf16tof(unsigned short b) {
    return __uint_as_float((unsigned int)b << 16);
}

// ---------------- GEMM: out[r][:] = (A[r][:] @ W) (+bias) (*scale[r]) ----------------
// OUTBF16: pack the row to bf16 (RNE), 128B/row.

template <bool HAS_BIAS, bool SCALE, bool OUTBF16>
__global__ void k_gemm64(const float* __restrict__ A, const float* __restrict__ W,
                         const float* __restrict__ bias, const float* __restrict__ scale,
                         void* __restrict__ out, int N) {
    __shared__ float Wl[64 * 64];
    int tid = threadIdx.x;
    {
        const float4* w4 = (const float4*)W;
        float4* wl4 = (float4*)Wl;
        for (int i = tid; i < 1024; i += 256) wl4[i] = w4[i];
    }
    __syncthreads();
    int r = blockIdx.x * 256 + tid;
    if (r >= N) return;

    float4 acc[16];
#pragma unroll
    for (int c4 = 0; c4 < 16; c4++) {
        if (HAS_BIAS) acc[c4] = ((const float4*)bias)[c4];
        else acc[c4] = make_float4(0.f, 0.f, 0.f, 0.f);
    }
    const float4* a4 = (const float4*)(A + (size_t)r * 64);
#pragma unroll 4
    for (int k4 = 0; k4 < 16; k4++) {
        float4 xv = a4[k4];
#pragma unroll
        for (int kk = 0; kk < 4; kk++) {
            float xk = (kk == 0) ? xv.x : (kk == 1) ? xv.y : (kk == 2) ? xv.z : xv.w;
            const float4* wr = (const float4*)(Wl + (k4 * 4 + kk) * 64);
#pragma unroll
            for (int c4 = 0; c4 < 16; c4++) {
                float4 w = wr[c4];
                acc[c4].x = fmaf(xk, w.x, acc[c4].x);
                acc[c4].y = fmaf(xk, w.y, acc[c4].y);
                acc[c4].z = fmaf(xk, w.z, acc[c4].z);
                acc[c4].w = fmaf(xk, w.w, acc[c4].w);
            }
        }
    }
    float s = SCALE ? scale[r] : 1.0f;
    if (OUTBF16) {
        uint2* o2 = (uint2*)((unsigned short*)out + (size_t)r * 64);
#pragma unroll
        for (int c4 = 0; c4 < 16; c4++) {
            float4 v = acc[c4];
            if (SCALE) { v.x *= s; v.y *= s; v.z *= s; v.w *= s; }
            unsigned int lo = bf16rne(v.x) | (bf16rne(v.y) << 16);
            unsigned int hi = bf16rne(v.z) | (bf16rne(v.w) << 16);
            o2[c4] = make_uint2(lo, hi);
        }
    } else {
        float4* o4 = (float4*)((float*)out + (size_t)r * 64);
#pragma unroll
        for (int c4 = 0; c4 < 16; c4++) {
            float4 v = acc[c4];
            if (SCALE) { v.x *= s; v.y *= s; v.z *= s; v.w *= s; }
            o4[c4] = v;
        }
    }
}

// ---------------- Aggregation: h[d] = dinv[d]*(hwb[d] + sum hwb[src]) + bg + h[d] ----------------
// hwb is bf16, pre-scaled by dinv[src]. One wave per node, lane = channel.

__global__ void k_agg(const unsigned short* __restrict__ hwb, const int* __restrict__ offs,
                      const int* __restrict__ col, const float* __restrict__ dinv,
                      const float* __restrict__ bg, float* __restrict__ h, int N, int relu) {
    int t = blockIdx.x * blockDim.x + threadIdx.x;
    int node = t >> 6;
    int c = t & 63;
    if (node >= N) return;
    int start = offs[node];
    int end = offs[node + 1];
    float acc = bf16tof(hwb[(size_t)node * 64 + c]);  // self-loop term
    int e = start;
    for (; e + 4 <= end; e += 4) {
        int s0 = col[e], s1 = col[e + 1], s2 = col[e + 2], s3 = col[e + 3];
        float v0 = bf16tof(hwb[(size_t)s0 * 64 + c]);
        float v1 = bf16tof(hwb[(size_t)s1 * 64 + c]);
        float v2 = bf16tof(hwb[(size_t)s2 * 64 + c]);
        float v3 = bf16tof(hwb[(size_t)s3 * 64 + c]);
        acc += v0 + v1 + v2 + v3;
    }
    for (; e < end; ++e) acc += bf16tof(hwb[(size_t)col[e] * 64 + c]);
    float r = fmaf(dinv[node], acc, bg[c] + h[(size_t)node * 64 + c]);
    if (relu) r = fmaxf(r, 0.f);
    h[(size_t)node * 64 + c] = r;
}

// ---------------- Fused MLP readout: 64 -> 32 -> 16 -> 1 (fully unrolled, no scratch) ----------------

__global__ __launch_bounds__(256)
void k_readout(const float* __restrict__ h,
               const float* __restrict__ W0, const float* __restrict__ b0,
               const float* __restrict__ W1, const float* __restrict__ b1,
               const float* __restrict__ W2, const float* __restrict__ b2,
               float* __restrict__ out, int N) {
    int r = blockIdx.x * 256 + threadIdx.x;
    if (r >= N) return;

    float t0[32];
#pragma unroll
    for (int c = 0; c < 32; c++) t0[c] = b0[c];

    const float4* h4 = (const float4*)(h + (size_t)r * 64);
#pragma unroll
    for (int k4 = 0; k4 < 16; k4++) {
        float4 v = h4[k4];
#pragma unroll
        for (int kk = 0; kk < 4; kk++) {
            float xk = (kk == 0) ? v.x : (kk == 1) ? v.y : (kk == 2) ? v.z : v.w;
            const float* wr = W0 + (k4 * 4 + kk) * 32;
#pragma unroll
            for (int c = 0; c < 32; c++) t0[c] = fmaf(xk, wr[c], t0[c]);
        }
    }
#pragma unroll
    for (int c = 0; c < 32; c++) t0[c] = fmaxf(t0[c], 0.f);

    float t1[16];
#pragma unroll
    for (int c = 0; c < 16; c++) t1[c] = b1[c];
#pragma unroll
    for (int k = 0; k < 32; k++) {
        const float* wr = W1 + k * 16;
#pragma unroll
        for (int c = 0; c < 16; c++) t1[c] = fmaf(t0[k], wr[c], t1[c]);
    }
#pragma unroll
    for (int c = 0; c < 16; c++) t1[c] = fmaxf(t1[c], 0.f);

    float y = b2[0];
#pragma unroll
    for (int k = 0; k < 16; k++) y = fmaf(t1[k], W2[k], y);
    out[r] = y;
}

// ---------------- launch ----------------

extern "C" void kernel_launch(void* const* d_in, const int* in_sizes, int n_in,
                              void* d_out, int out_size, void* d_ws, size_t ws_size,
                              hipStream_t stream) {
    const float* x     = (const float*)d_in[0];
    const int*   eidx  = (const int*)d_in[1];
    const float* W_enc = (const float*)d_in[2];
    const float* b_enc = (const float*)d_in[3];
    const float* Wg    = (const float*)d_in[4];
    const float* bg    = (const float*)d_in[5];
    const float* W0    = (const float*)d_in[6];
    const float* b0    = (const float*)d_in[7];
    const float* W1    = (const float*)d_in[8];
    const float* b1    = (const float*)d_in[9];
    const float* W2    = (const float*)d_in[10];
    const float* b2    = (const float*)d_in[11];

    int N = in_sizes[0] / 64;
    int E = in_sizes[1] / 2;
    const int* esrc = eidx;
    const int* edst = eidx + E;
    int nbuck = (N + 255) >> 8;

    char* w = (char*)d_ws;
    auto alloc = [&](size_t bytes) -> char* {
        char* p = w;
        w += (bytes + 255) & ~(size_t)255;
        return p;
    };
    int*   cnt  = (int*)alloc((size_t)N * 4);
    int*   offs = (int*)alloc((size_t)(N + 1) * 4);
    int*   bcur = (int*)alloc(512 * 4);
    int*   bsums = (int*)alloc(1024 * 4);
    int*   col  = (int*)alloc((size_t)E * 4);
    unsigned int* bpk = (unsigned int*)alloc((size_t)E * 4);
    float* dinv = (float*)alloc((size_t)N * 4);
    float* h    = (float*)alloc((size_t)N * 64 * 4);
    unsigned short* hwb = (unsigned short*)alloc((size_t)N * 64 * 2);

    hipMemsetAsync(cnt, 0, (size_t)N * 4, stream);

    const int TB = 256;
    k_count<<<(E + TB - 1) / TB, TB, 0, stream>>>(edst, cnt, E);
    int nb = (N + 1023) / 1024;
    k_scan1<<<nb, 1024, 0, stream>>>(cnt, offs, bsums, dinv, N);
    k_scan2<<<1, 128, 0, stream>>>(bsums, nb);
    k_scan3<<<nb, 1024, 0, stream>>>(offs, bsums, bcur, N, E);
    k_partition<<<(E + PCHUNK - 1) / PCHUNK, PTHREADS, 0, stream>>>(esrc, edst, bcur, bpk, E, nbuck);
    k_finefill<<<nbuck, 1024, 0, stream>>>(bpk, offs, col, N);

    int gb = (N + 255) / 256;
    k_gemm64<true, false, false><<<gb, 256, 0, stream>>>(x, W_enc, b_enc, nullptr, h, N);
    for (int l = 0; l < 4; l++) {
        k_gemm64<false, true, true><<<gb, 256, 0, stream>>>(h, Wg + (size_t)l * 4096, nullptr, dinv, hwb, N);
        k_agg<<<((size_t)N * 64 + 255) / 256, 256, 0, stream>>>(
            hwb, offs, col, dinv, bg + (size_t)l * 64, h, N, (l != 3) ? 1 : 0);
    }
    k_readout<<<gb, 256, 0, stream>>>(h, W0, b0, W1, b1, W2, b2, (float*)d_out, N);
}

// Round 5
// 487.022 us; speedup vs baseline: 1.5412x; 1.1604x over previous
//
#include <hip/hip_runtime.h>

// ---------------- degree count ----------------

__global__ void k_count(const int* __restrict__ dst, int* __restrict__ cnt, int E) {
    int e = blockIdx.x * blockDim.x + threadIdx.x;
    if (e < E) atomicAdd(&cnt[dst[e]], 1);
}

// ---------------- hierarchical scan (+ dinv, + bucket cursors) ----------------

__global__ void k_scan1(const int* __restrict__ cnt, int* __restrict__ offs,
                        int* __restrict__ bsums, float* __restrict__ dinv, int N) {
    __shared__ int tmp[1024];
    int tid = threadIdx.x;
    int i = blockIdx.x * 1024 + tid;
    int v = (i < N) ? cnt[i] : 0;
    if (i < N) dinv[i] = rsqrtf((float)(v + 1));  // +1 self-loop
    tmp[tid] = v;
    __syncthreads();
    for (int d = 1; d < 1024; d <<= 1) {
        int t = (tid >= d) ? tmp[tid - d] : 0;
        __syncthreads();
        tmp[tid] += t;
        __syncthreads();
    }
    if (i < N) offs[i] = tmp[tid] - v;          // block-local exclusive
    if (tid == 1023) bsums[blockIdx.x] = tmp[1023];
}

__global__ void k_scan2(int* bsums, int nb) {
    __shared__ int tmp[128];
    int tid = threadIdx.x;
    int v = (tid < nb) ? bsums[tid] : 0;
    tmp[tid] = v;
    __syncthreads();
    for (int d = 1; d < 128; d <<= 1) {
        int t = (tid >= d) ? tmp[tid - d] : 0;
        __syncthreads();
        tmp[tid] += t;
        __syncthreads();
    }
    if (tid < nb) bsums[tid] = tmp[tid] - v;    // exclusive block offsets
}

__global__ void k_scan3(int* __restrict__ offs, const int* __restrict__ bsums,
                        int* __restrict__ bcur, int N, int E) {
    int i = blockIdx.x * 1024 + threadIdx.x;
    if (i < N) {
        int o = offs[i] + bsums[blockIdx.x];
        offs[i] = o;
        if ((i & 255) == 0) bcur[i >> 8] = o;   // bucket region cursor = CSR base
    }
    if (i == 0) offs[N] = E;
}

// ---------------- partition: edges -> coarse buckets (256 nodes each) ----------------

#define PCHUNK 8192
#define PTHREADS 512
#define NBUCK_MAX 400

__global__ __launch_bounds__(PTHREADS)
void k_partition(const int* __restrict__ src, const int* __restrict__ dst,
                 int* __restrict__ bcur, unsigned int* __restrict__ bpk,
                 int E, int nbuck) {
    __shared__ int hist[NBUCK_MAX];
    __shared__ int boffs[NBUCK_MAX];
    __shared__ int cur[NBUCK_MAX];
    __shared__ int gbase[NBUCK_MAX];
    __shared__ int tmp[PTHREADS];
    __shared__ unsigned int stage[PCHUNK];
    __shared__ unsigned short sbid[PCHUNK];

    int tid = threadIdx.x;
    int ebase = blockIdx.x * PCHUNK;
    int ecount = min(PCHUNK, E - ebase);

    if (tid < NBUCK_MAX) hist[tid] = 0;
    __syncthreads();

    int dreg[16], sreg[16];
#pragma unroll
    for (int k = 0; k < 16; k++) {
        int e = ebase + tid + k * PTHREADS;
        if (tid + k * PTHREADS < ecount) {
            dreg[k] = dst[e];
            sreg[k] = src[e];
            atomicAdd(&hist[dreg[k] >> 8], 1);
        } else dreg[k] = -1;
    }
    __syncthreads();

    int v = (tid < nbuck) ? hist[tid] : 0;
    tmp[tid] = v;
    __syncthreads();
    for (int d = 1; d < PTHREADS; d <<= 1) {
        int t = (tid >= d) ? tmp[tid - d] : 0;
        __syncthreads();
        tmp[tid] += t;
        __syncthreads();
    }
    if (tid < nbuck) { boffs[tid] = tmp[tid] - v; cur[tid] = tmp[tid] - v; }
    __syncthreads();

#pragma unroll
    for (int k = 0; k < 16; k++) {
        if (dreg[k] >= 0) {
            int b = dreg[k] >> 8;
            int p = atomicAdd(&cur[b], 1);
            stage[p] = ((unsigned int)(dreg[k] & 255) << 17) | (unsigned int)sreg[k];
            sbid[p] = (unsigned short)b;
        }
    }
    __syncthreads();

    if (tid < nbuck) {
        int c = cur[tid] - boffs[tid];
        if (c > 0) gbase[tid] = atomicAdd(&bcur[tid], c);
    }
    __syncthreads();

    for (int i = tid; i < ecount; i += PTHREADS) {
        int b = sbid[i];
        bpk[gbase[b] + (i - boffs[b])] = stage[i];
    }
}

// ---------------- fine fill: bucket-grouped -> exact per-node CSR col[] ----------------

#define FCAP 6144

__global__ __launch_bounds__(1024)
void k_finefill(const unsigned int* __restrict__ bpk, const int* __restrict__ offs,
                int* __restrict__ col, int N) {
    __shared__ int cur[256];
    __shared__ unsigned int stage[FCAP];
    int b = blockIdx.x;
    int tid = threadIdx.x;
    int nbase = b << 8;
    int nend = min(nbase + 256, N);
    int nn = nend - nbase;
    int base = offs[nbase];
    int bedges = offs[nend] - base;

    if (tid < nn) cur[tid] = offs[nbase + tid] - base;
    __syncthreads();

    if (bedges <= FCAP) {
        for (int i = tid; i < bedges; i += 1024) {
            unsigned int v = bpk[base + i];
            int dl = v >> 17;
            int p = atomicAdd(&cur[dl], 1);
            stage[p] = v & 0x1FFFFu;
        }
        __syncthreads();
        for (int i = tid; i < bedges; i += 1024)
            col[base + i] = (int)stage[i];
    } else {
        for (int i = tid; i < bedges; i += 1024) {
            unsigned int v = bpk[base + i];
            int dl = v >> 17;
            int p = atomicAdd(&cur[dl], 1);
            col[base + p] = (int)(v & 0x1FFFFu);
        }
    }
}

// ---------------- bf16 helpers ----------------

__device__ __forceinline__ unsigned int bf16rne(float x) {
    unsigned int u = __float_as_uint(x);
    return (u + 0x7FFFu + ((u >> 16) & 1u)) >> 16;
}
__device__ __forceinline__ float u2flo(unsigned int u) { return __uint_as_float(u << 16); }
__device__ __forceinline__ float u2fhi(unsigned int u) { return __uint_as_float(u & 0xFFFF0000u); }

// ---------------- GEMM: out[r][:] = (A[r][:] @ W) (+bias) (*scale[r]) ----------------

template <bool HAS_BIAS, bool SCALE, bool OUTBF16>
__global__ void k_gemm64(const float* __restrict__ A, const float* __restrict__ W,
                         const float* __restrict__ bias, const float* __restrict__ scale,
                         void* __restrict__ out, int N) {
    __shared__ float Wl[64 * 64];
    int tid = threadIdx.x;
    {
        const float4* w4 = (const float4*)W;
        float4* wl4 = (float4*)Wl;
        for (int i = tid; i < 1024; i += 256) wl4[i] = w4[i];
    }
    __syncthreads();
    int r = blockIdx.x * 256 + tid;
    if (r >= N) return;

    float4 acc[16];
#pragma unroll
    for (int c4 = 0; c4 < 16; c4++) {
        if (HAS_BIAS) acc[c4] = ((const float4*)bias)[c4];
        else acc[c4] = make_float4(0.f, 0.f, 0.f, 0.f);
    }
    const float4* a4 = (const float4*)(A + (size_t)r * 64);
#pragma unroll 4
    for (int k4 = 0; k4 < 16; k4++) {
        float4 xv = a4[k4];
#pragma unroll
        for (int kk = 0; kk < 4; kk++) {
            float xk = (kk == 0) ? xv.x : (kk == 1) ? xv.y : (kk == 2) ? xv.z : xv.w;
            const float4* wr = (const float4*)(Wl + (k4 * 4 + kk) * 64);
#pragma unroll
            for (int c4 = 0; c4 < 16; c4++) {
                float4 w = wr[c4];
                acc[c4].x = fmaf(xk, w.x, acc[c4].x);
                acc[c4].y = fmaf(xk, w.y, acc[c4].y);
                acc[c4].z = fmaf(xk, w.z, acc[c4].z);
                acc[c4].w = fmaf(xk, w.w, acc[c4].w);
            }
        }
    }
    float s = SCALE ? scale[r] : 1.0f;
    if (OUTBF16) {
        uint2* o2 = (uint2*)((unsigned short*)out + (size_t)r * 64);
#pragma unroll
        for (int c4 = 0; c4 < 16; c4++) {
            float4 v = acc[c4];
            if (SCALE) { v.x *= s; v.y *= s; v.z *= s; v.w *= s; }
            unsigned int lo = bf16rne(v.x) | (bf16rne(v.y) << 16);
            unsigned int hi = bf16rne(v.z) | (bf16rne(v.w) << 16);
            o2[c4] = make_uint2(lo, hi);
        }
    } else {
        float4* o4 = (float4*)((float*)out + (size_t)r * 64);
#pragma unroll
        for (int c4 = 0; c4 < 16; c4++) {
            float4 v = acc[c4];
            if (SCALE) { v.x *= s; v.y *= s; v.z *= s; v.w *= s; }
            o4[c4] = v;
        }
    }
}

// ---------------- Aggregation ----------------
// h[d] = dinv[d]*(hwb[d] + sum_src hwb[src]) + bg + h[d]; hwb bf16 pre-scaled by dinv[src].
// One wave per node. 8 groups x 8 lanes: group G walks edges start+G, +8, ...;
// lane L loads uint4 = 8 channels (8 lanes x 16B = full 128B row). One wave-wide
// gather instruction covers 8 edges (1 KiB) -> ~5x fewer VMEM instrs, 16x more
// bytes in flight per wave. Butterfly shfl_xor(8,16,32) reduces groups at the end.

__global__ __launch_bounds__(256)
void k_agg(const unsigned short* __restrict__ hwb, const int* __restrict__ offs,
           const int* __restrict__ col, const float* __restrict__ dinv,
           const float* __restrict__ bg, float* __restrict__ h, int N, int relu) {
    int t = blockIdx.x * blockDim.x + threadIdx.x;
    int node = t >> 6;
    if (node >= N) return;
    int lane = t & 63;
    int G = lane >> 3;
    int L = lane & 7;

    int start = offs[node];
    int end = offs[node + 1];

    float a0 = 0.f, a1 = 0.f, a2 = 0.f, a3 = 0.f, a4 = 0.f, a5 = 0.f, a6 = 0.f, a7 = 0.f;

    if (G == 0) {  // self-loop term, counted once
        uint4 v = ((const uint4*)(hwb + (size_t)node * 64))[L];
        a0 = u2flo(v.x); a1 = u2fhi(v.x);
        a2 = u2flo(v.y); a3 = u2fhi(v.y);
        a4 = u2flo(v.z); a5 = u2fhi(v.z);
        a6 = u2flo(v.w); a7 = u2fhi(v.w);
    }

    int e = start + G;
    for (; e + 8 < end; e += 16) {  // 2x unrolled: 2 KiB in flight per wave
        int s0 = col[e];
        int s1 = col[e + 8];
        uint4 v0 = ((const uint4*)(hwb + (size_t)s0 * 64))[L];
        uint4 v1 = ((const uint4*)(hwb + (size_t)s1 * 64))[L];
        a0 += u2flo(v0.x); a1 += u2fhi(v0.x);
        a2 += u2flo(v0.y); a3 += u2fhi(v0.y);
        a4 += u2flo(v0.z); a5 += u2fhi(v0.z);
        a6 += u2flo(v0.w); a7 += u2fhi(v0.w);
        a0 += u2flo(v1.x); a1 += u2fhi(v1.x);
        a2 += u2flo(v1.y); a3 += u2fhi(v1.y);
        a4 += u2flo(v1.z); a5 += u2fhi(v1.z);
        a6 += u2flo(v1.w); a7 += u2fhi(v1.w);
    }
    if (e < end) {
        int s0 = col[e];
        uint4 v0 = ((const uint4*)(hwb + (size_t)s0 * 64))[L];
        a0 += u2flo(v0.x); a1 += u2fhi(v0.x);
        a2 += u2flo(v0.y); a3 += u2fhi(v0.y);
        a4 += u2flo(v0.z); a5 += u2fhi(v0.z);
        a6 += u2flo(v0.w); a7 += u2fhi(v0.w);
    }

    // reduce across the 8 groups (lane bits 3..5)
#pragma unroll
    for (int m = 8; m <= 32; m <<= 1) {
        a0 += __shfl_xor(a0, m);
        a1 += __shfl_xor(a1, m);
        a2 += __shfl_xor(a2, m);
        a3 += __shfl_xor(a3, m);
        a4 += __shfl_xor(a4, m);
        a5 += __shfl_xor(a5, m);
        a6 += __shfl_xor(a6, m);
        a7 += __shfl_xor(a7, m);
    }

    if (G == 0) {
        float dn = dinv[node];
        float* hrow = h + (size_t)node * 64;
        float4 r0 = ((const float4*)hrow)[2 * L];
        float4 r1 = ((const float4*)hrow)[2 * L + 1];
        float4 b0 = ((const float4*)bg)[2 * L];
        float4 b1 = ((const float4*)bg)[2 * L + 1];
        float4 o0, o1;
        o0.x = fmaf(dn, a0, b0.x + r0.x);
        o0.y = fmaf(dn, a1, b0.y + r0.y);
        o0.z = fmaf(dn, a2, b0.z + r0.z);
        o0.w = fmaf(dn, a3, b0.w + r0.w);
        o1.x = fmaf(dn, a4, b1.x + r1.x);
        o1.y = fmaf(dn, a5, b1.y + r1.y);
        o1.z = fmaf(dn, a6, b1.z + r1.z);
        o1.w = fmaf(dn, a7, b1.w + r1.w);
        if (relu) {
            o0.x = fmaxf(o0.x, 0.f); o0.y = fmaxf(o0.y, 0.f);
            o0.z = fmaxf(o0.z, 0.f); o0.w = fmaxf(o0.w, 0.f);
            o1.x = fmaxf(o1.x, 0.f); o1.y = fmaxf(o1.y, 0.f);
            o1.z = fmaxf(o1.z, 0.f); o1.w = fmaxf(o1.w, 0.f);
        }
        ((float4*)hrow)[2 * L] = o0;
        ((float4*)hrow)[2 * L + 1] = o1;
    }
}

// ---------------- Fused MLP readout: 64 -> 32 -> 16 -> 1 (fully unrolled, no scratch) ----------------

__global__ __launch_bounds__(256)
void k_readout(const float* __restrict__ h,
               const float* __restrict__ W0, const float* __restrict__ b0,
               const float* __restrict__ W1, const float* __restrict__ b1,
               const float* __restrict__ W2, const float* __restrict__ b2,
               float* __restrict__ out, int N) {
    int r = blockIdx.x * 256 + threadIdx.x;
    if (r >= N) return;

    float t0[32];
#pragma unroll
    for (int c = 0; c < 32; c++) t0[c] = b0[c];

    const float4* h4 = (const float4*)(h + (size_t)r * 64);
#pragma unroll
    for (int k4 = 0; k4 < 16; k4++) {
        float4 v = h4[k4];
#pragma unroll
        for (int kk = 0; kk < 4; kk++) {
            float xk = (kk == 0) ? v.x : (kk == 1) ? v.y : (kk == 2) ? v.z : v.w;
            const float* wr = W0 + (k4 * 4 + kk) * 32;
#pragma unroll
            for (int c = 0; c < 32; c++) t0[c] = fmaf(xk, wr[c], t0[c]);
        }
    }
#pragma unroll
    for (int c = 0; c < 32; c++) t0[c] = fmaxf(t0[c], 0.f);

    float t1[16];
#pragma unroll
    for (int c = 0; c < 16; c++) t1[c] = b1[c];
#pragma unroll
    for (int k = 0; k < 32; k++) {
        const float* wr = W1 + k * 16;
#pragma unroll
        for (int c = 0; c < 16; c++) t1[c] = fmaf(t0[k], wr[c], t1[c]);
    }
#pragma unroll
    for (int c = 0; c < 16; c++) t1[c] = fmaxf(t1[c], 0.f);

    float y = b2[0];
#pragma unroll
    for (int k = 0; k < 16; k++) y = fmaf(t1[k], W2[k], y);
    out[r] = y;
}

// ---------------- launch ----------------

extern "C" void kernel_launch(void* const* d_in, const int* in_sizes, int n_in,
                              void* d_out, int out_size, void* d_ws, size_t ws_size,
                              hipStream_t stream) {
    const float* x     = (const float*)d_in[0];
    const int*   eidx  = (const int*)d_in[1];
    const float* W_enc = (const float*)d_in[2];
    const float* b_enc = (const float*)d_in[3];
    const float* Wg    = (const float*)d_in[4];
    const float* bg    = (const float*)d_in[5];
    const float* W0    = (const float*)d_in[6];
    const float* b0    = (const float*)d_in[7];
    const float* W1    = (const float*)d_in[8];
    const float* b1    = (const float*)d_in[9];
    const float* W2    = (const float*)d_in[10];
    const float* b2    = (const float*)d_in[11];

    int N = in_sizes[0] / 64;
    int E = in_sizes[1] / 2;
    const int* esrc = eidx;
    const int* edst = eidx + E;
    int nbuck = (N + 255) >> 8;

    char* w = (char*)d_ws;
    auto alloc = [&](size_t bytes) -> char* {
        char* p = w;
        w += (bytes + 255) & ~(size_t)255;
        return p;
    };
    int*   cnt  = (int*)alloc((size_t)N * 4);
    int*   offs = (int*)alloc((size_t)(N + 1) * 4);
    int*   bcur = (int*)alloc(512 * 4);
    int*   bsums = (int*)alloc(1024 * 4);
    int*   col  = (int*)alloc((size_t)E * 4);
    unsigned int* bpk = (unsigned int*)alloc((size_t)E * 4);
    float* dinv = (float*)alloc((size_t)N * 4);
    float* h    = (float*)alloc((size_t)N * 64 * 4);
    unsigned short* hwb = (unsigned short*)alloc((size_t)N * 64 * 2);

    hipMemsetAsync(cnt, 0, (size_t)N * 4, stream);

    const int TB = 256;
    k_count<<<(E + TB - 1) / TB, TB, 0, stream>>>(edst, cnt, E);
    int nb = (N + 1023) / 1024;
    k_scan1<<<nb, 1024, 0, stream>>>(cnt, offs, bsums, dinv, N);
    k_scan2<<<1, 128, 0, stream>>>(bsums, nb);
    k_scan3<<<nb, 1024, 0, stream>>>(offs, bsums, bcur, N, E);
    k_partition<<<(E + PCHUNK - 1) / PCHUNK, PTHREADS, 0, stream>>>(esrc, edst, bcur, bpk, E, nbuck);
    k_finefill<<<nbuck, 1024, 0, stream>>>(bpk, offs, col, N);

    int gb = (N + 255) / 256;
    k_gemm64<true, false, false><<<gb, 256, 0, stream>>>(x, W_enc, b_enc, nullptr, h, N);
    for (int l = 0; l < 4; l++) {
        k_gemm64<false, true, true><<<gb, 256, 0, stream>>>(h, Wg + (size_t)l * 4096, nullptr, dinv, hwb, N);
        k_agg<<<((size_t)N * 64 + 255) / 256, 256, 0, stream>>>(
            hwb, offs, col, dinv, bg + (size_t)l * 64, h, N, (l != 3) ? 1 : 0);
    }
    k_readout<<<gb, 256, 0, stream>>>(h, W0, b0, W1, b1, W2, b2, (float*)d_out, N);
}

// Round 6
// 421.941 us; speedup vs baseline: 1.7789x; 1.1542x over previous
//
#include <hip/hip_runtime.h>

// ---------------- partition: edges -> coarse buckets (256 nodes each) ----------------
// Bucket regions are FIXED-STRIDE (CAP per bucket) in stageg; bcnt[b] is both the
// allocation cursor and, at the end, the exact per-bucket edge count.

#define PCHUNK 8192
#define PTHREADS 512
#define NBUCK_MAX 400
#define BCAP 6144

__global__ __launch_bounds__(PTHREADS)
void k_partition2(const int* __restrict__ src, const int* __restrict__ dst,
                  int* __restrict__ bcnt, unsigned int* __restrict__ stageg,
                  int E, int nbuck) {
    __shared__ int hist[NBUCK_MAX];
    __shared__ int boffs[NBUCK_MAX];
    __shared__ int cur[NBUCK_MAX];
    __shared__ int gbase[NBUCK_MAX];
    __shared__ int tmp[PTHREADS];
    __shared__ unsigned int stage[PCHUNK];
    __shared__ unsigned short sbid[PCHUNK];

    int tid = threadIdx.x;
    int ebase = blockIdx.x * PCHUNK;
    int ecount = min(PCHUNK, E - ebase);

    if (tid < NBUCK_MAX) hist[tid] = 0;
    __syncthreads();

    int dreg[16], sreg[16];
#pragma unroll
    for (int k = 0; k < 16; k++) {
        int e = ebase + tid + k * PTHREADS;
        if (tid + k * PTHREADS < ecount) {
            dreg[k] = dst[e];
            sreg[k] = src[e];
            atomicAdd(&hist[dreg[k] >> 8], 1);
        } else dreg[k] = -1;
    }
    __syncthreads();

    // exclusive scan of hist[0..nbuck)
    int v = (tid < nbuck) ? hist[tid] : 0;
    tmp[tid] = v;
    __syncthreads();
    for (int d = 1; d < PTHREADS; d <<= 1) {
        int t = (tid >= d) ? tmp[tid - d] : 0;
        __syncthreads();
        tmp[tid] += t;
        __syncthreads();
    }
    if (tid < nbuck) { boffs[tid] = tmp[tid] - v; cur[tid] = tmp[tid] - v; }
    __syncthreads();

    // group edges by bucket in LDS
#pragma unroll
    for (int k = 0; k < 16; k++) {
        if (dreg[k] >= 0) {
            int b = dreg[k] >> 8;
            int p = atomicAdd(&cur[b], 1);
            stage[p] = ((unsigned int)(dreg[k] & 255) << 17) | (unsigned int)sreg[k];
            sbid[p] = (unsigned short)b;
        }
    }
    __syncthreads();

    // reserve space in each bucket's fixed-stride region
    if (tid < nbuck) {
        int c = cur[tid] - boffs[tid];
        if (c > 0) gbase[tid] = atomicAdd(&bcnt[tid], c);
    }
    __syncthreads();

    // flush (runs of same bucket are contiguous -> coalesced-ish)
    for (int i = tid; i < ecount; i += PTHREADS) {
        int b = sbid[i];
        stageg[(size_t)b * BCAP + gbase[b] + (i - boffs[b])] = stage[i];
    }
}

// ---------------- bucket scan: exclusive scan of bcnt -> bbase ----------------

__global__ __launch_bounds__(512)
void k_bucket_scan(const int* __restrict__ bcnt, int* __restrict__ bbase, int nbuck) {
    __shared__ int tmp[512];
    int tid = threadIdx.x;
    int v = (tid < nbuck) ? bcnt[tid] : 0;
    tmp[tid] = v;
    __syncthreads();
    for (int d = 1; d < 512; d <<= 1) {
        int t = (tid >= d) ? tmp[tid - d] : 0;
        __syncthreads();
        tmp[tid] += t;
        __syncthreads();
    }
    if (tid < nbuck) bbase[tid] = tmp[tid] - v;
    if (tid == nbuck - 1) bbase[nbuck] = tmp[tid];  // total = E
}

// ---------------- fine fill: bucket-staged -> dense CSR (offs, dinv, col) ----------------

__global__ __launch_bounds__(1024)
void k_finefill2(const unsigned int* __restrict__ stageg, const int* __restrict__ bcnt,
                 const int* __restrict__ bbase, int* __restrict__ offs,
                 float* __restrict__ dinv, int* __restrict__ col, int N, int nbuck) {
    __shared__ int cnt0[256];
    __shared__ int excl[256];
    __shared__ int cur[256];
    __shared__ unsigned int stage[BCAP];
    int b = blockIdx.x;
    int tid = threadIdx.x;
    int nbase = b << 8;
    int nn = min(256, N - nbase);
    int n = bcnt[b];
    int base = bbase[b];
    const unsigned int* sg = stageg + (size_t)b * BCAP;

    if (tid < 256) cnt0[tid] = 0;
    __syncthreads();

    // per-node histogram
    for (int i = tid; i < n; i += 1024)
        atomicAdd(&cnt0[sg[i] >> 17], 1);
    __syncthreads();

    // exclusive scan of 256 counts (block-wide barriers, guarded work)
    if (tid < 256) excl[tid] = cnt0[tid];
    __syncthreads();
    for (int d = 1; d < 256; d <<= 1) {
        int t = 0;
        if (tid < 256 && tid >= d) t = excl[tid - d];
        __syncthreads();
        if (tid < 256) excl[tid] += t;
        __syncthreads();
    }
    // excl now inclusive; convert and emit offs/dinv/cursors
    if (tid < 256) {
        int e = excl[tid] - cnt0[tid];
        cur[tid] = e;
        if (tid < nn) {
            offs[nbase + tid] = base + e;
            dinv[nbase + tid] = rsqrtf((float)(cnt0[tid] + 1));  // +1 self-loop
        }
    }
    if (b == nbuck - 1 && tid == 0) offs[N] = bbase[nbuck];
    __syncthreads();

    // scatter to per-node order in LDS, then dense flush
    for (int i = tid; i < n; i += 1024) {
        unsigned int v = sg[i];
        int p = atomicAdd(&cur[v >> 17], 1);
        stage[p] = v & 0x1FFFFu;
    }
    __syncthreads();
    for (int i = tid; i < n; i += 1024)
        col[base + i] = (int)stage[i];
}

// ---------------- bf16 helpers ----------------

__device__ __forceinline__ unsigned int bf16rne(float x) {
    unsigned int u = __float_as_uint(x);
    return (u + 0x7FFFu + ((u >> 16) & 1u)) >> 16;
}
__device__ __forceinline__ float u2flo(unsigned int u) { return __uint_as_float(u << 16); }
__device__ __forceinline__ float u2fhi(unsigned int u) { return __uint_as_float(u & 0xFFFF0000u); }

// ---------------- GEMM: out[r][:] = (A[r][:] @ W) (+bias) (*scale[r]) ----------------

template <bool HAS_BIAS, bool SCALE, bool OUTBF16>
__global__ void k_gemm64(const float* __restrict__ A, const float* __restrict__ W,
                         const float* __restrict__ bias, const float* __restrict__ scale,
                         void* __restrict__ out, int N) {
    __shared__ float Wl[64 * 64];
    int tid = threadIdx.x;
    {
        const float4* w4 = (const float4*)W;
        float4* wl4 = (float4*)Wl;
        for (int i = tid; i < 1024; i += 256) wl4[i] = w4[i];
    }
    __syncthreads();
    int r = blockIdx.x * 256 + tid;
    if (r >= N) return;

    float4 acc[16];
#pragma unroll
    for (int c4 = 0; c4 < 16; c4++) {
        if (HAS_BIAS) acc[c4] = ((const float4*)bias)[c4];
        else acc[c4] = make_float4(0.f, 0.f, 0.f, 0.f);
    }
    const float4* a4 = (const float4*)(A + (size_t)r * 64);
#pragma unroll 4
    for (int k4 = 0; k4 < 16; k4++) {
        float4 xv = a4[k4];
#pragma unroll
        for (int kk = 0; kk < 4; kk++) {
            float xk = (kk == 0) ? xv.x : (kk == 1) ? xv.y : (kk == 2) ? xv.z : xv.w;
            const float4* wr = (const float4*)(Wl + (k4 * 4 + kk) * 64);
#pragma unroll
            for (int c4 = 0; c4 < 16; c4++) {
                float4 w = wr[c4];
                acc[c4].x = fmaf(xk, w.x, acc[c4].x);
                acc[c4].y = fmaf(xk, w.y, acc[c4].y);
                acc[c4].z = fmaf(xk, w.z, acc[c4].z);
                acc[c4].w = fmaf(xk, w.w, acc[c4].w);
            }
        }
    }
    float s = SCALE ? scale[r] : 1.0f;
    if (OUTBF16) {
        uint2* o2 = (uint2*)((unsigned short*)out + (size_t)r * 64);
#pragma unroll
        for (int c4 = 0; c4 < 16; c4++) {
            float4 v = acc[c4];
            if (SCALE) { v.x *= s; v.y *= s; v.z *= s; v.w *= s; }
            unsigned int lo = bf16rne(v.x) | (bf16rne(v.y) << 16);
            unsigned int hi = bf16rne(v.z) | (bf16rne(v.w) << 16);
            o2[c4] = make_uint2(lo, hi);
        }
    } else {
        float4* o4 = (float4*)((float*)out + (size_t)r * 64);
#pragma unroll
        for (int c4 = 0; c4 < 16; c4++) {
            float4 v = acc[c4];
            if (SCALE) { v.x *= s; v.y *= s; v.z *= s; v.w *= s; }
            o4[c4] = v;
        }
    }
}

// ---------------- Aggregation (8 groups x 8 lanes, 1KiB/instr gather) ----------------

__global__ __launch_bounds__(256)
void k_agg(const unsigned short* __restrict__ hwb, const int* __restrict__ offs,
           const int* __restrict__ col, const float* __restrict__ dinv,
           const float* __restrict__ bg, float* __restrict__ h, int N, int relu) {
    int t = blockIdx.x * blockDim.x + threadIdx.x;
    int node = t >> 6;
    if (node >= N) return;
    int lane = t & 63;
    int G = lane >> 3;
    int L = lane & 7;

    int start = offs[node];
    int end = offs[node + 1];

    float a0 = 0.f, a1 = 0.f, a2 = 0.f, a3 = 0.f, a4 = 0.f, a5 = 0.f, a6 = 0.f, a7 = 0.f;

    if (G == 0) {  // self-loop term, counted once
        uint4 v = ((const uint4*)(hwb + (size_t)node * 64))[L];
        a0 = u2flo(v.x); a1 = u2fhi(v.x);
        a2 = u2flo(v.y); a3 = u2fhi(v.y);
        a4 = u2flo(v.z); a5 = u2fhi(v.z);
        a6 = u2flo(v.w); a7 = u2fhi(v.w);
    }

    int e = start + G;
    for (; e + 8 < end; e += 16) {
        int s0 = col[e];
        int s1 = col[e + 8];
        uint4 v0 = ((const uint4*)(hwb + (size_t)s0 * 64))[L];
        uint4 v1 = ((const uint4*)(hwb + (size_t)s1 * 64))[L];
        a0 += u2flo(v0.x); a1 += u2fhi(v0.x);
        a2 += u2flo(v0.y); a3 += u2fhi(v0.y);
        a4 += u2flo(v0.z); a5 += u2fhi(v0.z);
        a6 += u2flo(v0.w); a7 += u2fhi(v0.w);
        a0 += u2flo(v1.x); a1 += u2fhi(v1.x);
        a2 += u2flo(v1.y); a3 += u2fhi(v1.y);
        a4 += u2flo(v1.z); a5 += u2fhi(v1.z);
        a6 += u2flo(v1.w); a7 += u2fhi(v1.w);
    }
    if (e < end) {
        int s0 = col[e];
        uint4 v0 = ((const uint4*)(hwb + (size_t)s0 * 64))[L];
        a0 += u2flo(v0.x); a1 += u2fhi(v0.x);
        a2 += u2flo(v0.y); a3 += u2fhi(v0.y);
        a4 += u2flo(v0.z); a5 += u2fhi(v0.z);
        a6 += u2flo(v0.w); a7 += u2fhi(v0.w);
    }

#pragma unroll
    for (int m = 8; m <= 32; m <<= 1) {
        a0 += __shfl_xor(a0, m);
        a1 += __shfl_xor(a1, m);
        a2 += __shfl_xor(a2, m);
        a3 += __shfl_xor(a3, m);
        a4 += __shfl_xor(a4, m);
        a5 += __shfl_xor(a5, m);
        a6 += __shfl_xor(a6, m);
        a7 += __shfl_xor(a7, m);
    }

    if (G == 0) {
        float dn = dinv[node];
        float* hrow = h + (size_t)node * 64;
        float4 r0 = ((const float4*)hrow)[2 * L];
        float4 r1 = ((const float4*)hrow)[2 * L + 1];
        float4 b0 = ((const float4*)bg)[2 * L];
        float4 b1 = ((const float4*)bg)[2 * L + 1];
        float4 o0, o1;
        o0.x = fmaf(dn, a0, b0.x + r0.x);
        o0.y = fmaf(dn, a1, b0.y + r0.y);
        o0.z = fmaf(dn, a2, b0.z + r0.z);
        o0.w = fmaf(dn, a3, b0.w + r0.w);
        o1.x = fmaf(dn, a4, b1.x + r1.x);
        o1.y = fmaf(dn, a5, b1.y + r1.y);
        o1.z = fmaf(dn, a6, b1.z + r1.z);
        o1.w = fmaf(dn, a7, b1.w + r1.w);
        if (relu) {
            o0.x = fmaxf(o0.x, 0.f); o0.y = fmaxf(o0.y, 0.f);
            o0.z = fmaxf(o0.z, 0.f); o0.w = fmaxf(o0.w, 0.f);
            o1.x = fmaxf(o1.x, 0.f); o1.y = fmaxf(o1.y, 0.f);
            o1.z = fmaxf(o1.z, 0.f); o1.w = fmaxf(o1.w, 0.f);
        }
        ((float4*)hrow)[2 * L] = o0;
        ((float4*)hrow)[2 * L + 1] = o1;
    }
}

// ---------------- Fused MLP readout: 64 -> 32 -> 16 -> 1 (fully unrolled) ----------------

__global__ __launch_bounds__(256)
void k_readout(const float* __restrict__ h,
               const float* __restrict__ W0, const float* __restrict__ b0,
               const float* __restrict__ W1, const float* __restrict__ b1,
               const float* __restrict__ W2, const float* __restrict__ b2,
               float* __restrict__ out, int N) {
    int r = blockIdx.x * 256 + threadIdx.x;
    if (r >= N) return;

    float t0[32];
#pragma unroll
    for (int c = 0; c < 32; c++) t0[c] = b0[c];

    const float4* h4 = (const float4*)(h + (size_t)r * 64);
#pragma unroll
    for (int k4 = 0; k4 < 16; k4++) {
        float4 v = h4[k4];
#pragma unroll
        for (int kk = 0; kk < 4; kk++) {
            float xk = (kk == 0) ? v.x : (kk == 1) ? v.y : (kk == 2) ? v.z : v.w;
            const float* wr = W0 + (k4 * 4 + kk) * 32;
#pragma unroll
            for (int c = 0; c < 32; c++) t0[c] = fmaf(xk, wr[c], t0[c]);
        }
    }
#pragma unroll
    for (int c = 0; c < 32; c++) t0[c] = fmaxf(t0[c], 0.f);

    float t1[16];
#pragma unroll
    for (int c = 0; c < 16; c++) t1[c] = b1[c];
#pragma unroll
    for (int k = 0; k < 32; k++) {
        const float* wr = W1 + k * 16;
#pragma unroll
        for (int c = 0; c < 16; c++) t1[c] = fmaf(t0[k], wr[c], t1[c]);
    }
#pragma unroll
    for (int c = 0; c < 16; c++) t1[c] = fmaxf(t1[c], 0.f);

    float y = b2[0];
#pragma unroll
    for (int k = 0; k < 16; k++) y = fmaf(t1[k], W2[k], y);
    out[r] = y;
}

// ---------------- launch ----------------

extern "C" void kernel_launch(void* const* d_in, const int* in_sizes, int n_in,
                              void* d_out, int out_size, void* d_ws, size_t ws_size,
                              hipStream_t stream) {
    const float* x     = (const float*)d_in[0];
    const int*   eidx  = (const int*)d_in[1];
    const float* W_enc = (const float*)d_in[2];
    const float* b_enc = (const float*)d_in[3];
    const float* Wg    = (const float*)d_in[4];
    const float* bg    = (const float*)d_in[5];
    const float* W0    = (const float*)d_in[6];
    const float* b0    = (const float*)d_in[7];
    const float* W1    = (const float*)d_in[8];
    const float* b1    = (const float*)d_in[9];
    const float* W2    = (const float*)d_in[10];
    const float* b2    = (const float*)d_in[11];

    int N = in_sizes[0] / 64;
    int E = in_sizes[1] / 2;
    const int* esrc = eidx;
    const int* edst = eidx + E;
    int nbuck = (N + 255) >> 8;

    char* w = (char*)d_ws;
    auto alloc = [&](size_t bytes) -> char* {
        char* p = w;
        w += (bytes + 255) & ~(size_t)255;
        return p;
    };
    int*   bcnt  = (int*)alloc(512 * 4);
    int*   bbase = (int*)alloc(512 * 4);
    int*   offs  = (int*)alloc((size_t)(N + 1) * 4);
    int*   col   = (int*)alloc((size_t)E * 4);
    unsigned int* stageg = (unsigned int*)alloc((size_t)nbuck * BCAP * 4);
    float* dinv  = (float*)alloc((size_t)N * 4);
    float* h     = (float*)alloc((size_t)N * 64 * 4);
    unsigned short* hwb = (unsigned short*)alloc((size_t)N * 64 * 2);

    hipMemsetAsync(bcnt, 0, 512 * 4, stream);

    k_partition2<<<(E + PCHUNK - 1) / PCHUNK, PTHREADS, 0, stream>>>(esrc, edst, bcnt, stageg, E, nbuck);
    k_bucket_scan<<<1, 512, 0, stream>>>(bcnt, bbase, nbuck);
    k_finefill2<<<nbuck, 1024, 0, stream>>>(stageg, bcnt, bbase, offs, dinv, col, N, nbuck);

    int gb = (N + 255) / 256;
    k_gemm64<true, false, false><<<gb, 256, 0, stream>>>(x, W_enc, b_enc, nullptr, h, N);
    for (int l = 0; l < 4; l++) {
        k_gemm64<false, true, true><<<gb, 256, 0, stream>>>(h, Wg + (size_t)l * 4096, nullptr, dinv, hwb, N);
        k_agg<<<((size_t)N * 64 + 255) / 256, 256, 0, stream>>>(
            hwb, offs, col, dinv, bg + (size_t)l * 64, h, N, (l != 3) ? 1 : 0);
    }
    k_readout<<<gb, 256, 0, stream>>>(h, W0, b0, W1, b1, W2, b2, (float*)d_out, N);
}

// Round 7
// 384.079 us; speedup vs baseline: 1.9543x; 1.0986x over previous
//
#include <hip/hip_runtime.h>

// ---------------- partition: edges -> coarse buckets (256 nodes each) ----------------

#define PCHUNK 8192
#define PTHREADS 512
#define NBUCK_MAX 400
#define BCAP 6144

__global__ __launch_bounds__(PTHREADS)
void k_partition2(const int* __restrict__ src, const int* __restrict__ dst,
                  int* __restrict__ bcnt, unsigned int* __restrict__ stageg,
                  int E, int nbuck) {
    __shared__ int hist[NBUCK_MAX];
    __shared__ int boffs[NBUCK_MAX];
    __shared__ int cur[NBUCK_MAX];
    __shared__ int gbase[NBUCK_MAX];
    __shared__ int tmp[PTHREADS];
    __shared__ unsigned int stage[PCHUNK];
    __shared__ unsigned short sbid[PCHUNK];

    int tid = threadIdx.x;
    int ebase = blockIdx.x * PCHUNK;
    int ecount = min(PCHUNK, E - ebase);

    if (tid < NBUCK_MAX) hist[tid] = 0;
    __syncthreads();

    int dreg[16], sreg[16];
#pragma unroll
    for (int k = 0; k < 16; k++) {
        int e = ebase + tid + k * PTHREADS;
        if (tid + k * PTHREADS < ecount) {
            dreg[k] = dst[e];
            sreg[k] = src[e];
            atomicAdd(&hist[dreg[k] >> 8], 1);
        } else dreg[k] = -1;
    }
    __syncthreads();

    int v = (tid < nbuck) ? hist[tid] : 0;
    tmp[tid] = v;
    __syncthreads();
    for (int d = 1; d < PTHREADS; d <<= 1) {
        int t = (tid >= d) ? tmp[tid - d] : 0;
        __syncthreads();
        tmp[tid] += t;
        __syncthreads();
    }
    if (tid < nbuck) { boffs[tid] = tmp[tid] - v; cur[tid] = tmp[tid] - v; }
    __syncthreads();

#pragma unroll
    for (int k = 0; k < 16; k++) {
        if (dreg[k] >= 0) {
            int b = dreg[k] >> 8;
            int p = atomicAdd(&cur[b], 1);
            stage[p] = ((unsigned int)(dreg[k] & 255) << 17) | (unsigned int)sreg[k];
            sbid[p] = (unsigned short)b;
        }
    }
    __syncthreads();

    if (tid < nbuck) {
        int c = cur[tid] - boffs[tid];
        if (c > 0) gbase[tid] = atomicAdd(&bcnt[tid], c);
    }
    __syncthreads();

    for (int i = tid; i < ecount; i += PTHREADS) {
        int b = sbid[i];
        stageg[(size_t)b * BCAP + gbase[b] + (i - boffs[b])] = stage[i];
    }
}

// ---------------- bucket scan ----------------

__global__ __launch_bounds__(512)
void k_bucket_scan(const int* __restrict__ bcnt, int* __restrict__ bbase, int nbuck) {
    __shared__ int tmp[512];
    int tid = threadIdx.x;
    int v = (tid < nbuck) ? bcnt[tid] : 0;
    tmp[tid] = v;
    __syncthreads();
    for (int d = 1; d < 512; d <<= 1) {
        int t = (tid >= d) ? tmp[tid - d] : 0;
        __syncthreads();
        tmp[tid] += t;
        __syncthreads();
    }
    if (tid < nbuck) bbase[tid] = tmp[tid] - v;
    if (tid == nbuck - 1) bbase[nbuck] = tmp[tid];
}

// ---------------- fine fill: bucket-staged -> dense CSR (offs, dinv, col) ----------------

__global__ __launch_bounds__(1024)
void k_finefill2(const unsigned int* __restrict__ stageg, const int* __restrict__ bcnt,
                 const int* __restrict__ bbase, int* __restrict__ offs,
                 float* __restrict__ dinv, int* __restrict__ col, int N, int nbuck) {
    __shared__ int cnt0[256];
    __shared__ int excl[256];
    __shared__ int cur[256];
    __shared__ unsigned int stage[BCAP];
    int b = blockIdx.x;
    int tid = threadIdx.x;
    int nbase = b << 8;
    int nn = min(256, N - nbase);
    int n = bcnt[b];
    int base = bbase[b];
    const unsigned int* sg = stageg + (size_t)b * BCAP;

    if (tid < 256) cnt0[tid] = 0;
    __syncthreads();

    for (int i = tid; i < n; i += 1024)
        atomicAdd(&cnt0[sg[i] >> 17], 1);
    __syncthreads();

    if (tid < 256) excl[tid] = cnt0[tid];
    __syncthreads();
    for (int d = 1; d < 256; d <<= 1) {
        int t = 0;
        if (tid < 256 && tid >= d) t = excl[tid - d];
        __syncthreads();
        if (tid < 256) excl[tid] += t;
        __syncthreads();
    }
    if (tid < 256) {
        int e = excl[tid] - cnt0[tid];
        cur[tid] = e;
        if (tid < nn) {
            offs[nbase + tid] = base + e;
            dinv[nbase + tid] = rsqrtf((float)(cnt0[tid] + 1));  // +1 self-loop
        }
    }
    if (b == nbuck - 1 && tid == 0) offs[N] = bbase[nbuck];
    __syncthreads();

    for (int i = tid; i < n; i += 1024) {
        unsigned int v = sg[i];
        int p = atomicAdd(&cur[v >> 17], 1);
        stage[p] = v & 0x1FFFFu;
    }
    __syncthreads();
    for (int i = tid; i < n; i += 1024)
        col[base + i] = (int)stage[i];
}

// ---------------- bf16 helpers ----------------

__device__ __forceinline__ unsigned int bf16rne(float x) {
    unsigned int u = __float_as_uint(x);
    return (u + 0x7FFFu + ((u >> 16) & 1u)) >> 16;
}
__device__ __forceinline__ float u2flo(unsigned int u) { return __uint_as_float(u << 16); }
__device__ __forceinline__ float u2fhi(unsigned int u) { return __uint_as_float(u & 0xFFFF0000u); }

// ---------------- GEMM: out[r][:] = (A[r][:] @ W) (+bias) (*scale[r]) ----------------

template <bool HAS_BIAS, bool SCALE, bool OUTBF16>
__global__ void k_gemm64(const float* __restrict__ A, const float* __restrict__ W,
                         const float* __restrict__ bias, const float* __restrict__ scale,
                         void* __restrict__ out, int N) {
    __shared__ float Wl[64 * 64];
    int tid = threadIdx.x;
    {
        const float4* w4 = (const float4*)W;
        float4* wl4 = (float4*)Wl;
        for (int i = tid; i < 1024; i += 256) wl4[i] = w4[i];
    }
    __syncthreads();
    int r = blockIdx.x * 256 + tid;
    if (r >= N) return;

    float4 acc[16];
#pragma unroll
    for (int c4 = 0; c4 < 16; c4++) {
        if (HAS_BIAS) acc[c4] = ((const float4*)bias)[c4];
        else acc[c4] = make_float4(0.f, 0.f, 0.f, 0.f);
    }
    const float4* a4 = (const float4*)(A + (size_t)r * 64);
#pragma unroll 4
    for (int k4 = 0; k4 < 16; k4++) {
        float4 xv = a4[k4];
#pragma unroll
        for (int kk = 0; kk < 4; kk++) {
            float xk = (kk == 0) ? xv.x : (kk == 1) ? xv.y : (kk == 2) ? xv.z : xv.w;
            const float4* wr = (const float4*)(Wl + (k4 * 4 + kk) * 64);
#pragma unroll
            for (int c4 = 0; c4 < 16; c4++) {
                float4 w = wr[c4];
                acc[c4].x = fmaf(xk, w.x, acc[c4].x);
                acc[c4].y = fmaf(xk, w.y, acc[c4].y);
                acc[c4].z = fmaf(xk, w.z, acc[c4].z);
                acc[c4].w = fmaf(xk, w.w, acc[c4].w);
            }
        }
    }
    float s = SCALE ? scale[r] : 1.0f;
    if (OUTBF16) {
        uint2* o2 = (uint2*)((unsigned short*)out + (size_t)r * 64);
#pragma unroll
        for (int c4 = 0; c4 < 16; c4++) {
            float4 v = acc[c4];
            if (SCALE) { v.x *= s; v.y *= s; v.z *= s; v.w *= s; }
            unsigned int lo = bf16rne(v.x) | (bf16rne(v.y) << 16);
            unsigned int hi = bf16rne(v.z) | (bf16rne(v.w) << 16);
            o2[c4] = make_uint2(lo, hi);
        }
    } else {
        float4* o4 = (float4*)((float*)out + (size_t)r * 64);
#pragma unroll
        for (int c4 = 0; c4 < 16; c4++) {
            float4 v = acc[c4];
            if (SCALE) { v.x *= s; v.y *= s; v.z *= s; v.w *= s; }
            o4[c4] = v;
        }
    }
}

// ---------------- Aggregation: one wave per 8 NODES ----------------
// Group G (8 lanes) owns node wid*8+G and walks its whole edge list; lane L
// accumulates channels [L*8, L*8+8). Gather instruction shape unchanged
// (8 rows x 128B = 1KiB per instr) but each wave now sustains 8 independent
// edge chains (16 gathers in flight with 2x unroll) for its whole lifetime,
// and the shfl_xor butterfly + masked epilogue disappear.

__global__ __launch_bounds__(256)
void k_agg(const unsigned short* __restrict__ hwb, const int* __restrict__ offs,
           const int* __restrict__ col, const float* __restrict__ dinv,
           const float* __restrict__ bg, float* __restrict__ h, int N, int relu) {
    int t = blockIdx.x * blockDim.x + threadIdx.x;
    int wid = t >> 6;
    int lane = threadIdx.x & 63;
    int G = lane >> 3;
    int L = lane & 7;
    int node = wid * 8 + G;
    bool valid = node < N;
    int nc = valid ? node : N - 1;

    int start = offs[nc];
    int end = valid ? offs[nc + 1] : start;

    // self-loop row (counted once; discarded for invalid lanes)
    uint4 v = ((const uint4*)(hwb + (size_t)nc * 64))[L];
    float a0 = u2flo(v.x), a1 = u2fhi(v.x);
    float a2 = u2flo(v.y), a3 = u2fhi(v.y);
    float a4 = u2flo(v.z), a5 = u2fhi(v.z);
    float a6 = u2flo(v.w), a7 = u2fhi(v.w);

    for (int e = start;; e += 2) {
        bool act0 = e < end;
        if (__ballot(act0) == 0ULL) break;
        bool act1 = e + 1 < end;
        int e0 = act0 ? e : 0;
        int e1 = act1 ? e + 1 : 0;
        int s0 = col[e0];
        int s1 = col[e1];
        uint4 v0 = ((const uint4*)(hwb + (size_t)s0 * 64))[L];
        uint4 v1 = ((const uint4*)(hwb + (size_t)s1 * 64))[L];
        if (!act0) { v0.x = 0u; v0.y = 0u; v0.z = 0u; v0.w = 0u; }  // bf16 0x0000 == 0.0f
        if (!act1) { v1.x = 0u; v1.y = 0u; v1.z = 0u; v1.w = 0u; }
        a0 += u2flo(v0.x) + u2flo(v1.x);
        a1 += u2fhi(v0.x) + u2fhi(v1.x);
        a2 += u2flo(v0.y) + u2flo(v1.y);
        a3 += u2fhi(v0.y) + u2fhi(v1.y);
        a4 += u2flo(v0.z) + u2flo(v1.z);
        a5 += u2fhi(v0.z) + u2fhi(v1.z);
        a6 += u2flo(v0.w) + u2flo(v1.w);
        a7 += u2fhi(v0.w) + u2fhi(v1.w);
    }

    if (valid) {
        float dn = dinv[node];
        float* hrow = h + (size_t)node * 64 + L * 8;
        float4 r0 = ((const float4*)hrow)[0];
        float4 r1 = ((const float4*)hrow)[1];
        const float* bgp = bg + L * 8;
        float4 b0 = ((const float4*)bgp)[0];
        float4 b1 = ((const float4*)bgp)[1];
        float4 o0, o1;
        o0.x = fmaf(dn, a0, b0.x + r0.x);
        o0.y = fmaf(dn, a1, b0.y + r0.y);
        o0.z = fmaf(dn, a2, b0.z + r0.z);
        o0.w = fmaf(dn, a3, b0.w + r0.w);
        o1.x = fmaf(dn, a4, b1.x + r1.x);
        o1.y = fmaf(dn, a5, b1.y + r1.y);
        o1.z = fmaf(dn, a6, b1.z + r1.z);
        o1.w = fmaf(dn, a7, b1.w + r1.w);
        if (relu) {
            o0.x = fmaxf(o0.x, 0.f); o0.y = fmaxf(o0.y, 0.f);
            o0.z = fmaxf(o0.z, 0.f); o0.w = fmaxf(o0.w, 0.f);
            o1.x = fmaxf(o1.x, 0.f); o1.y = fmaxf(o1.y, 0.f);
            o1.z = fmaxf(o1.z, 0.f); o1.w = fmaxf(o1.w, 0.f);
        }
        ((float4*)hrow)[0] = o0;
        ((float4*)hrow)[1] = o1;
    }
}

// ---------------- Fused MLP readout: 64 -> 32 -> 16 -> 1 (fully unrolled) ----------------

__global__ __launch_bounds__(256)
void k_readout(const float* __restrict__ h,
               const float* __restrict__ W0, const float* __restrict__ b0,
               const float* __restrict__ W1, const float* __restrict__ b1,
               const float* __restrict__ W2, const float* __restrict__ b2,
               float* __restrict__ out, int N) {
    int r = blockIdx.x * 256 + threadIdx.x;
    if (r >= N) return;

    float t0[32];
#pragma unroll
    for (int c = 0; c < 32; c++) t0[c] = b0[c];

    const float4* h4 = (const float4*)(h + (size_t)r * 64);
#pragma unroll
    for (int k4 = 0; k4 < 16; k4++) {
        float4 v = h4[k4];
#pragma unroll
        for (int kk = 0; kk < 4; kk++) {
            float xk = (kk == 0) ? v.x : (kk == 1) ? v.y : (kk == 2) ? v.z : v.w;
            const float* wr = W0 + (k4 * 4 + kk) * 32;
#pragma unroll
            for (int c = 0; c < 32; c++) t0[c] = fmaf(xk, wr[c], t0[c]);
        }
    }
#pragma unroll
    for (int c = 0; c < 32; c++) t0[c] = fmaxf(t0[c], 0.f);

    float t1[16];
#pragma unroll
    for (int c = 0; c < 16; c++) t1[c] = b1[c];
#pragma unroll
    for (int k = 0; k < 32; k++) {
        const float* wr = W1 + k * 16;
#pragma unroll
        for (int c = 0; c < 16; c++) t1[c] = fmaf(t0[k], wr[c], t1[c]);
    }
#pragma unroll
    for (int c = 0; c < 16; c++) t1[c] = fmaxf(t1[c], 0.f);

    float y = b2[0];
#pragma unroll
    for (int k = 0; k < 16; k++) y = fmaf(t1[k], W2[k], y);
    out[r] = y;
}

// ---------------- launch ----------------

extern "C" void kernel_launch(void* const* d_in, const int* in_sizes, int n_in,
                              void* d_out, int out_size, void* d_ws, size_t ws_size,
                              hipStream_t stream) {
    const float* x     = (const float*)d_in[0];
    const int*   eidx  = (const int*)d_in[1];
    const float* W_enc = (const float*)d_in[2];
    const float* b_enc = (const float*)d_in[3];
    const float* Wg    = (const float*)d_in[4];
    const float* bg    = (const float*)d_in[5];
    const float* W0    = (const float*)d_in[6];
    const float* b0    = (const float*)d_in[7];
    const float* W1    = (const float*)d_in[8];
    const float* b1    = (const float*)d_in[9];
    const float* W2    = (const float*)d_in[10];
    const float* b2    = (const float*)d_in[11];

    int N = in_sizes[0] / 64;
    int E = in_sizes[1] / 2;
    const int* esrc = eidx;
    const int* edst = eidx + E;
    int nbuck = (N + 255) >> 8;

    char* w = (char*)d_ws;
    auto alloc = [&](size_t bytes) -> char* {
        char* p = w;
        w += (bytes + 255) & ~(size_t)255;
        return p;
    };
    int*   bcnt  = (int*)alloc(512 * 4);
    int*   bbase = (int*)alloc(512 * 4);
    int*   offs  = (int*)alloc((size_t)(N + 1) * 4);
    int*   col   = (int*)alloc((size_t)E * 4);
    unsigned int* stageg = (unsigned int*)alloc((size_t)nbuck * BCAP * 4);
    float* dinv  = (float*)alloc((size_t)N * 4);
    float* h     = (float*)alloc((size_t)N * 64 * 4);
    unsigned short* hwb = (unsigned short*)alloc((size_t)N * 64 * 2);

    hipMemsetAsync(bcnt, 0, 512 * 4, stream);

    k_partition2<<<(E + PCHUNK - 1) / PCHUNK, PTHREADS, 0, stream>>>(esrc, edst, bcnt, stageg, E, nbuck);
    k_bucket_scan<<<1, 512, 0, stream>>>(bcnt, bbase, nbuck);
    k_finefill2<<<nbuck, 1024, 0, stream>>>(stageg, bcnt, bbase, offs, dinv, col, N, nbuck);

    int gb = (N + 255) / 256;
    // agg: one wave per 8 nodes
    int aggthreads = ((N + 7) / 8) * 64;
    int aggblocks = (aggthreads + 255) / 256;
    k_gemm64<true, false, false><<<gb, 256, 0, stream>>>(x, W_enc, b_enc, nullptr, h, N);
    for (int l = 0; l < 4; l++) {
        k_gemm64<false, true, true><<<gb, 256, 0, stream>>>(h, Wg + (size_t)l * 4096, nullptr, dinv, hwb, N);
        k_agg<<<aggblocks, 256, 0, stream>>>(
            hwb, offs, col, dinv, bg + (size_t)l * 64, h, N, (l != 3) ? 1 : 0);
    }
    k_readout<<<gb, 256, 0, stream>>>(h, W0, b0, W1, b1, W2, b2, (float*)d_out, N);
}